// Round 2
// baseline (295.800 us; speedup 1.0000x reference)
//
#include <hip/hip_runtime.h>
#include <hip/hip_bf16.h>
#include <stdint.h>

#define Bn 2
#define Np 50000
#define Cc 81
#define CM1 80
#define KSEL 2048
#define NDET 100
#define NBUCK 4096
#define BUCK_BASE 0x3D000000u
#define BUCK_SHIFT 14
#define SELCAP 4096
#define IMG_W 1333.0f
#define IMG_H 800.0f
#define SCORE_TH 0.05f
#define MIN_SZ 0.01f
#define NMS_TH 0.5f
#define LBLOFF 1401.0f
#define BBOX_CLIP_F 4.135166556742356f
#define PPW 8   // proposals per wave in pass1

typedef unsigned long long u64;
typedef unsigned int u32;

__device__ __forceinline__ u64 shfl64(u64 v, int src) {
  int lo = __shfl((int)(u32)v, src, 64);
  int hi = __shfl((int)(u32)(v >> 32), src, 64);
  return ((u64)(u32)hi << 32) | (u32)lo;
}

// Torchvision BoxCoder.decode + clip, non-contracted fp32 to match reference.
__device__ __forceinline__ void decode_box(int row, int c,
    const float* __restrict__ reg, const float* __restrict__ props,
    float& x1, float& y1, float& x2, float& y2) {
  const float* pr = props + (size_t)row * 4;
  float px1 = pr[0], py1 = pr[1], px2 = pr[2], py2 = pr[3];
  float w = __fsub_rn(px2, px1), h = __fsub_rn(py2, py1);
  float cx = __fadd_rn(px1, 0.5f * w), cy = __fadd_rn(py1, 0.5f * h);
  const float4 rel = *reinterpret_cast<const float4*>(reg + ((size_t)row * Cc + c) * 4);
  float dx = __fdiv_rn(rel.x, 10.f), dy = __fdiv_rn(rel.y, 10.f);
  float dw = fminf(__fdiv_rn(rel.z, 5.f), BBOX_CLIP_F);
  float dh = fminf(__fdiv_rn(rel.w, 5.f), BBOX_CLIP_F);
  float pcx = __fadd_rn(__fmul_rn(dx, w), cx);
  float pcy = __fadd_rn(__fmul_rn(dy, h), cy);
  float pw = __fmul_rn(expf(dw), w);
  float ph = __fmul_rn(expf(dh), h);
  x1 = fminf(fmaxf(__fsub_rn(pcx, 0.5f * pw), 0.f), IMG_W);
  y1 = fminf(fmaxf(__fsub_rn(pcy, 0.5f * ph), 0.f), IMG_H);
  x2 = fminf(fmaxf(__fadd_rn(pcx, 0.5f * pw), 0.f), IMG_W);
  y2 = fminf(fmaxf(__fadd_rn(pcy, 0.5f * ph), 0.f), IMG_H);
}

// Pass 1: wave-per-proposal (keeps the exact xor-tree softmax reduce that
// bit-matched the reference). Per-wave private LDS buffer + register count +
// ballot-prefix compaction: no __syncthreads, no shared counters. Histogram
// atomics go straight to global (scattered over 4096 buckets).
__global__ __launch_bounds__(256) void pass1_kernel(
    const float* __restrict__ logits, const float* __restrict__ reg,
    const float* __restrict__ props, u64* __restrict__ cand,
    u32* __restrict__ gcnt, u32* __restrict__ ghist, int cap)
{
  __shared__ u64 lbuf[4][512];
  const int b = blockIdx.y;
  const int wave = threadIdx.x >> 6, lane = threadIdx.x & 63;
  u64* wbuf = lbuf[wave];
  u32 cnt = 0;
  const int base_n = (blockIdx.x * 4 + wave) * PPW;
  for (int p = 0; p < PPW; ++p) {
    const int n = base_n + p;
    if (n >= Np) break;
    const int row = b * Np + n;
    const float* lrow = logits + (size_t)row * Cc;
    float l0 = lrow[lane];
    float l1 = (lane < Cc - 64) ? lrow[64 + lane] : -3.4e38f;
    float mx = fmaxf(l0, l1);
    #pragma unroll
    for (int o = 32; o; o >>= 1) mx = fmaxf(mx, __shfl_xor(mx, o, 64));
    float e0 = expf(l0 - mx);
    float e1 = (lane < Cc - 64) ? expf(l1 - mx) : 0.f;
    float s = e0 + e1;
    #pragma unroll
    for (int o = 32; o; o >>= 1) s += __shfl_xor(s, o, 64);
    const float thr = SCORE_TH * s;
    #pragma unroll
    for (int slot = 0; slot < 2; ++slot) {
      const int c = slot ? (64 + lane) : lane;
      const float e = slot ? e1 : e0;
      bool emit = false;
      u64 key = 0; u32 bk = 0;
      if (c >= 1 && c < Cc && e > thr) {
        float x1, y1, x2, y2;
        decode_box(row, c, reg, props, x1, y1, x2, y2);
        if (__fsub_rn(x2, x1) >= MIN_SZ && __fsub_rn(y2, y1) >= MIN_SZ) {
          const float score = __fdiv_rn(e, s);
          const u32 sb = __float_as_uint(score);
          const u32 idx = (u32)(n * CM1 + (c - 1));
          key = ((u64)sb << 32) | (u32)(~idx);
          bk = (sb - BUCK_BASE) >> BUCK_SHIFT;
          if (bk > (u32)(NBUCK - 1)) bk = NBUCK - 1;
          emit = true;
        }
      }
      const u64 bal = __ballot(emit);
      if (emit) {
        const u32 pos = cnt + (u32)__popcll(bal & ((1ull << lane) - 1ull));
        wbuf[pos] = key;
        atomicAdd(&ghist[b * NBUCK + bk], 1u);
      }
      cnt += (u32)__popcll(bal);
    }
    if (cnt >= 512u - 80u) {
      u32 gb = 0;
      if (lane == 0) gb = atomicAdd(&gcnt[b], cnt);
      gb = (u32)__shfl((int)gb, 0, 64);
      for (u32 i = lane; i < cnt; i += 64) {
        const u32 pp = gb + i;
        if (pp < (u32)cap) cand[(size_t)b * cap + pp] = wbuf[i];
      }
      cnt = 0;
    }
  }
  if (cnt) {
    u32 gb = 0;
    if (lane == 0) gb = atomicAdd(&gcnt[b], cnt);
    gb = (u32)__shfl((int)gb, 0, 64);
    for (u32 i = lane; i < cnt; i += 64) {
      const u32 pp = gb + i;
      if (pp < (u32)cap) cand[(size_t)b * cap + pp] = wbuf[i];
    }
  }
}

// Per image: T = largest bucket with inclusive suffix-count >= KSEL (0 if
// total < KSEL), plus per-bucket exclusive suffix offsets for counting sort.
__global__ void thresh_kernel(const u32* __restrict__ ghist, u32* __restrict__ gT,
                              u32* __restrict__ boffs) {
  const int b = blockIdx.x;
  const int lane = threadIdx.x;  // 64 threads
  const u32* h = ghist + b * NBUCK;
  u32* bo = boffs + b * NBUCK;
  const int SEG = NBUCK / 64;
  u32 segsum = 0;
  for (int t = 0; t < SEG; ++t) segsum += h[lane * SEG + t];
  u32 suf = segsum;
  #pragma unroll
  for (int o = 1; o < 64; o <<= 1) {
    u32 v = (u32)__shfl_down((int)suf, o, 64);
    if (lane + o < 64) suf += v;
  }
  u32 acc = suf - segsum;   // count in buckets strictly above this segment
  int myT = -1;
  for (int t = SEG - 1; t >= 0; --t) {
    const int bk = lane * SEG + t;
    bo[bk] = acc;
    acc += h[bk];
    if (myT < 0 && acc >= (u32)KSEL) myT = bk;
  }
  int T = myT;
  #pragma unroll
  for (int o = 32; o; o >>= 1) T = max(T, __shfl_xor(T, o, 64));
  if (lane == 0) gT[b] = (T < 0) ? 0u : (u32)T;
}

// Counting-sort scatter: key -> skeys[boffs[bucket] + fill], bucket-descending.
__global__ __launch_bounds__(256) void scatter_kernel(
    const u64* __restrict__ cand, const u32* __restrict__ gcnt,
    const u32* __restrict__ gT, const u32* __restrict__ boffs,
    u32* __restrict__ bfill, u64* __restrict__ skeys, int cap)
{
  const int b = blockIdx.y;
  u32 cnt = gcnt[b];
  if (cnt > (u32)cap) cnt = (u32)cap;
  const u32 i = blockIdx.x * 256 + threadIdx.x;
  if (i >= cnt) return;
  const u64 key = cand[(size_t)b * cap + i];
  const u32 sb = (u32)(key >> 32);
  u32 bk = (sb - BUCK_BASE) >> BUCK_SHIFT;
  if (bk > (u32)(NBUCK - 1)) bk = NBUCK - 1;
  if (bk >= gT[b]) {
    const u32 pos = boffs[b * NBUCK + bk] + atomicAdd(&bfill[b * NBUCK + bk], 1u);
    if (pos < (u32)SELCAP) skeys[(size_t)b * SELCAP + pos] = key;
  }
}

// Tiny per-bucket selection sorts (runs avg ~7) complete the descending
// order, then decode the top-2048 into the SoA sel_data.
__global__ __launch_bounds__(256) void bsort_decode_kernel(
    u64* __restrict__ skeys, const u32* __restrict__ gT,
    const u32* __restrict__ boffs, const u32* __restrict__ bfill,
    const float* __restrict__ reg, const float* __restrict__ props,
    float* __restrict__ sel_data)
{
  const int b = blockIdx.x;
  const int tid = threadIdx.x;
  const u32 T = gT[b];
  u64* sk = skeys + (size_t)b * SELCAP;
  for (u32 bk = T + tid; bk < (u32)NBUCK; bk += 256) {
    const u32 start = boffs[b * NBUCK + bk];
    u32 rcnt = bfill[b * NBUCK + bk];
    if (start >= (u32)KSEL) continue;           // run fully beyond output
    if (start + rcnt > (u32)SELCAP) rcnt = SELCAP - start;
    if (rcnt < 2) continue;
    u64* run = sk + start;
    for (u32 a = 0; a + 1 < rcnt; ++a) {
      u32 mi = a; u64 mv = run[a];
      for (u32 q = a + 1; q < rcnt; ++q) { const u64 v = run[q]; if (v > mv) { mv = v; mi = q; } }
      if (mi != a) { run[mi] = run[a]; run[a] = mv; }
    }
  }
  __syncthreads();
  float* S = sel_data + (size_t)b * 12 * KSEL;
  for (int t = tid; t < KSEL; t += 256) {
    const u64 key = sk[t];
    float x1 = 0, y1 = 0, x2 = 0, y2 = 0, score = 0, lab = 0;
    if (key) {
      const u32 sb = (u32)(key >> 32);
      const u32 idx = ~(u32)key;
      const int n_ = (int)(idx / CM1);
      const int c = (int)(idx % CM1) + 1;
      score = __uint_as_float(sb);
      decode_box(b * Np + n_, c, reg, props, x1, y1, x2, y2);
      lab = (float)c;
    }
    const float offv = __fmul_rn(lab, LBLOFF);
    const float ox1 = __fadd_rn(x1, offv), oy1 = __fadd_rn(y1, offv);
    const float ox2 = __fadd_rn(x2, offv), oy2 = __fadd_rn(y2, offv);
    const float area = __fmul_rn(__fsub_rn(ox2, ox1), __fsub_rn(oy2, oy1));
    S[0*KSEL+t]=x1;  S[1*KSEL+t]=y1;  S[2*KSEL+t]=x2;  S[3*KSEL+t]=y2;
    S[4*KSEL+t]=ox1; S[5*KSEL+t]=oy1; S[6*KSEL+t]=ox2; S[7*KSEL+t]=oy2;
    S[8*KSEL+t]=area; S[9*KSEL+t]=score; S[10*KSEL+t]=lab;
  }
}

// Suppression matrix: one wave per row i, lane j computes iou(i, t*64+j),
// __ballot IS the 64-bit mask word.
__global__ __launch_bounds__(256) void mask_kernel(
    const float* __restrict__ sel_data, u64* __restrict__ mask)
{
  __shared__ float sx1[KSEL], sy1[KSEL], sx2[KSEL], sy2[KSEL], sar[KSEL];
  const int b = blockIdx.y;
  const float* S = sel_data + (size_t)b * 12 * KSEL;
  for (int i = threadIdx.x; i < KSEL; i += 256) {
    sx1[i] = S[4*KSEL+i]; sy1[i] = S[5*KSEL+i];
    sx2[i] = S[6*KSEL+i]; sy2[i] = S[7*KSEL+i];
    sar[i] = S[8*KSEL+i];
  }
  __syncthreads();
  const int wave = threadIdx.x >> 6, lane = threadIdx.x & 63;
  const int i = blockIdx.x * 4 + wave;
  const float ix1 = sx1[i], iy1 = sy1[i], ix2 = sx2[i], iy2 = sy2[i], ia = sar[i];
  u64* mrow = mask + ((size_t)(b * KSEL + i)) * 32;
  for (int t = 0; t < 32; ++t) {
    const int j = (t << 6) + lane;
    const float ltx = fmaxf(ix1, sx1[j]), lty = fmaxf(iy1, sy1[j]);
    const float rbx = fminf(ix2, sx2[j]), rby = fminf(iy2, sy2[j]);
    const float wx = fmaxf(__fsub_rn(rbx, ltx), 0.f);
    const float wy = fmaxf(__fsub_rn(rby, lty), 0.f);
    const float inter = __fmul_rn(wx, wy);
    const float denom = __fadd_rn(__fsub_rn(__fadd_rn(ia, sar[j]), inter), 1e-9f);
    const float iou = __fdiv_rn(inter, denom);
    const u64 word = __ballot(iou > NMS_TH);
    if (lane == 0) mrow[t] = word;
  }
}

// Greedy NMS over sorted candidates, early-exit at 100 keeps, write outputs.
// Fixed-trip unrolled loops so ds/bpermute and mask-row loads pipeline.
__global__ __launch_bounds__(64) void nms_out_kernel(
    const float* __restrict__ sel_data, const u64* __restrict__ mask,
    float* __restrict__ out)
{
  const int b = blockIdx.x;
  const int lane = threadIdx.x;
  const float* S = sel_data + (size_t)b * 12 * KSEL;
  __shared__ unsigned short keptIdx[NDET];
  u64 R = 0;   // lanes 0..31 hold the running removed-mask words
  int kc = 0;
  for (int c = 0; c < 32; ++c) {
    const int i = (c << 6) + lane;
    const u64 mword = mask[((size_t)(b * KSEL + i)) * 32 + c];
    const bool valid = S[9 * KSEL + i] > 0.f;
    const u64 vm = __ballot(valid);
    const u64 Rc = shfl64(R, c);
    u64 rem = Rc, keepm = 0;
    #pragma unroll
    for (int j = 0; j < 64; ++j) {
      const u64 mj = shfl64(mword, j);
      if (!((rem >> j) & 1ull) && ((vm >> j) & 1ull)) {
        keepm |= 1ull << j;
        rem |= mj;
      }
    }
    if ((keepm >> lane) & 1ull) {
      const int pos = kc + __popcll(keepm & ((1ull << lane) - 1ull));
      if (pos < NDET) keptIdx[pos] = (unsigned short)i;
    }
    kc += __popcll(keepm);
    if (kc >= NDET) break;
    u64 acc = 0;
    if (lane < 32) {
      const u64* mbase = mask + ((size_t)(b * KSEL + (c << 6))) * 32 + lane;
      #pragma unroll
      for (int j = 0; j < 64; ++j)
        if ((keepm >> j) & 1ull) acc |= mbase[(size_t)j * 32];
    }
    R |= acc;
  }
  __syncthreads();
  const int kcl = (kc < NDET) ? kc : NDET;
  for (int k = lane; k < NDET; k += 64) {
    float bx1 = 0, by1 = 0, bx2 = 0, by2 = 0, sc = 0, lb = -1.f;
    if (k < kcl) {
      const int i = keptIdx[k];
      bx1 = S[0*KSEL+i]; by1 = S[1*KSEL+i]; bx2 = S[2*KSEL+i]; by2 = S[3*KSEL+i];
      sc = S[9*KSEL+i];  lb = S[10*KSEL+i];
    }
    float* ob = out + (size_t)b * NDET * 4;
    ob[k*4+0] = bx1; ob[k*4+1] = by1; ob[k*4+2] = bx2; ob[k*4+3] = by2;
    out[Bn*NDET*4 + b*NDET + k] = sc;
    out[Bn*NDET*4 + Bn*NDET + b*NDET + k] = lb;
  }
}

extern "C" void kernel_launch(void* const* d_in, const int* in_sizes, int n_in,
                              void* d_out, int out_size, void* d_ws, size_t ws_size,
                              hipStream_t stream) {
  const float* logits = (const float*)d_in[0];
  const float* reg    = (const float*)d_in[1];
  const float* props  = (const float*)d_in[2];
  float* out = (float*)d_out;
  char* ws = (char*)d_ws;

  // Workspace layout (prefix [0, memset_bytes) is zeroed every call):
  u32* gcnt  = (u32*)ws;                       // 2
  u32* gT    = (u32*)(ws + 8);                 // 2
  size_t off = 64;
  u32* ghist = (u32*)(ws + off); off += (size_t)Bn * NBUCK * 4;   // 32 KB
  u32* bfill = (u32*)(ws + off); off += (size_t)Bn * NBUCK * 4;   // 32 KB
  off = (off + 255) & ~(size_t)255;
  u64* skeys = (u64*)(ws + off); off += (size_t)Bn * SELCAP * 8;  // 64 KB
  const size_t memset_bytes = off;
  u32* boffs = (u32*)(ws + off); off += (size_t)Bn * NBUCK * 4;   // 32 KB
  float* sel_data = (float*)(ws + off); off += (size_t)Bn * 12 * KSEL * 4;
  off = (off + 255) & ~(size_t)255;
  u64* mask = (u64*)(ws + off); off += (size_t)Bn * KSEL * 32 * 8;
  size_t remain = (ws_size > off) ? (ws_size - off) : 0;
  size_t capz = remain / ((size_t)Bn * 8);
  int cap = (capz > (size_t)(1 << 19)) ? (1 << 19) : (int)capz;
  if (cap < 1) cap = 1;
  u64* cand = (u64*)(ws + off);

  hipMemsetAsync(d_ws, 0, memset_bytes, stream);
  const int blocks_x = (Np + 4 * PPW - 1) / (4 * PPW);
  pass1_kernel<<<dim3(blocks_x, Bn), 256, 0, stream>>>(logits, reg, props, cand, gcnt, ghist, cap);
  thresh_kernel<<<dim3(Bn), 64, 0, stream>>>(ghist, gT, boffs);
  scatter_kernel<<<dim3((u32)((cap + 255) / 256), Bn), 256, 0, stream>>>(cand, gcnt, gT, boffs, bfill, skeys, cap);
  bsort_decode_kernel<<<dim3(Bn), 256, 0, stream>>>(skeys, gT, boffs, bfill, reg, props, sel_data);
  mask_kernel<<<dim3(KSEL / 4, Bn), 256, 0, stream>>>(sel_data, mask);
  nms_out_kernel<<<dim3(Bn), 64, 0, stream>>>(sel_data, mask, out);
}

// Round 3
// 290.249 us; speedup vs baseline: 1.0191x; 1.0191x over previous
//
#include <hip/hip_runtime.h>
#include <hip/hip_bf16.h>
#include <stdint.h>

#define Bn 2
#define Np 50000
#define Cc 81
#define CM1 80
#define KSEL 2048
#define NDET 100
#define NBUCK 2048
#define BUCK_BASE 0x3D000000u
#define BUCK_SHIFT 15
#define SELCAP 4096
#define IMG_W 1333.0f
#define IMG_H 800.0f
#define SCORE_TH 0.05f
#define MIN_SZ 0.01f
#define NMS_TH 0.5f
#define LBLOFF 1401.0f
#define BBOX_CLIP_F 4.135166556742356f
#define CHUNK 16
#define QCAP 128

typedef unsigned long long u64;
typedef unsigned int u32;

__device__ __forceinline__ u64 shfl64(u64 v, int src) {
  int lo = __shfl((int)(u32)v, src, 64);
  int hi = __shfl((int)(u32)(v >> 32), src, 64);
  return ((u64)(u32)hi << 32) | (u32)lo;
}

// Torchvision BoxCoder.decode + clip, non-contracted fp32 to match reference.
__device__ __forceinline__ void decode_box(int row, int c,
    const float* __restrict__ reg, const float* __restrict__ props,
    float& x1, float& y1, float& x2, float& y2) {
  const float4 pr = *reinterpret_cast<const float4*>(props + (size_t)row * 4);
  float w = __fsub_rn(pr.z, pr.x), h = __fsub_rn(pr.w, pr.y);
  float cx = __fadd_rn(pr.x, 0.5f * w), cy = __fadd_rn(pr.y, 0.5f * h);
  const float4 rel = *reinterpret_cast<const float4*>(reg + ((size_t)row * Cc + c) * 4);
  float dx = __fdiv_rn(rel.x, 10.f), dy = __fdiv_rn(rel.y, 10.f);
  float dw = fminf(__fdiv_rn(rel.z, 5.f), BBOX_CLIP_F);
  float dh = fminf(__fdiv_rn(rel.w, 5.f), BBOX_CLIP_F);
  float pcx = __fadd_rn(__fmul_rn(dx, w), cx);
  float pcy = __fadd_rn(__fmul_rn(dy, h), cy);
  float pw = __fmul_rn(expf(dw), w);
  float ph = __fmul_rn(expf(dh), h);
  x1 = fminf(fmaxf(__fsub_rn(pcx, 0.5f * pw), 0.f), IMG_W);
  y1 = fminf(fmaxf(__fsub_rn(pcy, 0.5f * ph), 0.f), IMG_H);
  x2 = fminf(fmaxf(__fadd_rn(pcx, 0.5f * pw), 0.f), IMG_W);
  y2 = fminf(fmaxf(__fadd_rn(pcy, 0.5f * ph), 0.f), IMG_H);
}

// Batched drain: 64 lanes each decode+filter one queued (score,~idx) key,
// compact survivors to global cand (one gcnt atomic per drain), count into
// the block-shared LDS histogram. Keeps scattered atomics out of the
// softmax loop's vmcnt window.
__device__ __forceinline__ void drain(const u64* Qb, u32 n, int lane, int b,
    const float* __restrict__ reg, const float* __restrict__ props,
    u32* hist, u64* candb, u32* gcnt, int cap) {
  const bool act = lane < (int)n;
  u64 key = 0;
  if (act) key = Qb[lane];
  bool valid = false;
  u32 sb = 0;
  if (act) {
    sb = (u32)(key >> 32);
    const u32 idx = ~(u32)key;
    const int n_ = (int)(idx / CM1);
    const int c = (int)(idx - (u32)n_ * CM1) + 1;
    float x1, y1, x2, y2;
    decode_box(b * Np + n_, c, reg, props, x1, y1, x2, y2);
    valid = (__fsub_rn(x2, x1) >= MIN_SZ) && (__fsub_rn(y2, y1) >= MIN_SZ);
  }
  const u64 bal = __ballot(valid);
  const u32 nv = (u32)__popcll(bal);
  if (!nv) return;
  u32 gb = 0;
  if (lane == 0) gb = atomicAdd(gcnt, nv);
  gb = (u32)__shfl((int)gb, 0, 64);
  if (valid) {
    const u32 pos = gb + (u32)__popcll(bal & ((1ull << lane) - 1ull));
    if (pos < (u32)cap) candb[pos] = key;
    u32 bk = (sb - BUCK_BASE) >> BUCK_SHIFT;
    if (bk > (u32)(NBUCK - 1)) bk = NBUCK - 1;
    atomicAdd(&hist[bk], 1u);
  }
}

// Pass 1: thread-per-proposal, quad-split. Wave stages 16 proposals x 81
// logits to its private LDS slab (6 coalesced float4 loads), 4 lanes per
// proposal reduce 21 classes in registers (max exact; sum order relaxed,
// ulp-level only). Emits -> per-wave LDS queue -> batched drain.
__global__ __launch_bounds__(256, 4) void pass1_kernel(
    const float* __restrict__ logits, const float* __restrict__ reg,
    const float* __restrict__ props, u64* __restrict__ cand,
    u32* __restrict__ gcnt, u32* __restrict__ ghist, int cap)
{
  __shared__ __align__(16) float stg[4][CHUNK * Cc];   // 20736 B
  __shared__ u64 qbuf[4][QCAP];                        // 4096 B
  __shared__ u32 hist[NBUCK];                          // 8192 B
  const int b = blockIdx.y;
  const int tid = threadIdx.x;
  const int wave = tid >> 6, lane = tid & 63;
  for (int i = tid; i < NBUCK; i += 256) hist[i] = 0;
  __syncthreads();

  const int n0 = ((blockIdx.x << 2) + wave) * CHUNK;
  u64* candb = cand + (size_t)b * cap;
  if (n0 < Np) {
    float* S = stg[wave];
    u64* Q = qbuf[wave];
    u32 qcnt = 0;
    // --- stage: 16 rows x 81 floats = 324 float4, coalesced ---
    const float* src = logits + ((size_t)b * Np + n0) * Cc;
    #pragma unroll
    for (int i = 0; i < 6; ++i) {
      const int f4 = i * 64 + lane;
      if (f4 < (CHUNK * Cc) / 4) {
        const float4 v = *reinterpret_cast<const float4*>(src + (size_t)f4 * 4);
        *reinterpret_cast<float4*>(&S[f4 * 4]) = v;
      }
    }
    // --- per-lane: proposal p = lane>>2, quarter qd = lane&3 ---
    const int p = lane >> 2, qd = lane & 3;
    const int base = p * Cc + qd * 21;
    const int cnt_k = (qd == 3) ? 18 : 21;
    float ev[21];
    #pragma unroll
    for (int k = 0; k < 21; ++k)
      ev[k] = (k < cnt_k) ? S[base + k] : -3.4e38f;
    float m = ev[0];
    #pragma unroll
    for (int k = 1; k < 21; ++k) m = fmaxf(m, ev[k]);
    m = fmaxf(m, __shfl_xor(m, 1, 64));
    m = fmaxf(m, __shfl_xor(m, 2, 64));
    float s = 0.f;
    #pragma unroll
    for (int k = 0; k < 21; ++k) {
      ev[k] = (k < cnt_k) ? expf(ev[k] - m) : 0.f;
      s += ev[k];
    }
    s += __shfl_xor(s, 1, 64);
    s += __shfl_xor(s, 2, 64);
    const float thr = SCORE_TH * s;
    const int n_ = n0 + p;
    #pragma unroll
    for (int k = 0; k < 21; ++k) {
      const int c = qd * 21 + k;
      const bool emit = (c > 0) && (ev[k] > thr);
      u64 key = 0;
      if (emit) {
        const float sc = __fdiv_rn(ev[k], s);
        const u32 idx = (u32)(n_ * CM1 + (c - 1));
        key = ((u64)__float_as_uint(sc) << 32) | (u32)(~idx);
      }
      const u64 bal = __ballot(emit);
      if (emit) Q[qcnt + (u32)__popcll(bal & ((1ull << lane) - 1ull))] = key;
      qcnt += (u32)__popcll(bal);
      if (qcnt >= 64u) {
        qcnt -= 64u;
        drain(Q + qcnt, 64u, lane, b, reg, props, hist, candb, &gcnt[b], cap);
      }
    }
    if (qcnt) drain(Q, qcnt, lane, b, reg, props, hist, candb, &gcnt[b], cap);
  }
  __syncthreads();
  for (int i = tid; i < NBUCK; i += 256) {
    const u32 v = hist[i];
    if (v) atomicAdd(&ghist[b * NBUCK + i], v);
  }
}

// Per image: T = largest bucket with inclusive suffix >= KSEL (0 if total
// < KSEL); per-bucket exclusive suffix offsets; total selected (clamped).
__global__ void thresh_kernel(const u32* __restrict__ ghist, u32* __restrict__ gT,
                              u32* __restrict__ gTot, u32* __restrict__ boffs) {
  const int b = blockIdx.x;
  const int lane = threadIdx.x;  // 64 threads
  const u32* h = ghist + b * NBUCK;
  u32* bo = boffs + b * NBUCK;
  const int SEG = NBUCK / 64;
  u32 segsum = 0;
  for (int t = 0; t < SEG; ++t) segsum += h[lane * SEG + t];
  u32 suf = segsum;
  #pragma unroll
  for (int o = 1; o < 64; o <<= 1) {
    const u32 v = (u32)__shfl_down((int)suf, o, 64);
    if (lane + o < 64) suf += v;
  }
  u32 acc = suf - segsum;   // buckets strictly above this segment
  int myT = -1; u32 totv = 0;
  for (int t = SEG - 1; t >= 0; --t) {
    const int bk = lane * SEG + t;
    bo[bk] = acc;
    acc += h[bk];
    if (myT < 0 && acc >= (u32)KSEL) { myT = bk; totv = acc; }
  }
  int Tg = myT;
  #pragma unroll
  for (int o = 32; o; o >>= 1) Tg = max(Tg, __shfl_xor(Tg, o, 64));
  if (Tg < 0) {
    if (lane == 0) { gT[b] = 0u; gTot[b] = (acc < (u32)SELCAP) ? acc : (u32)SELCAP; }
  } else if (myT == Tg) {
    gT[b] = (u32)Tg;
    gTot[b] = (totv < (u32)SELCAP) ? totv : (u32)SELCAP;
  }
}

// Counting-sort scatter (grid-stride): key -> skeys[boffs[bucket] + fill].
__global__ __launch_bounds__(256) void scatter_kernel(
    const u64* __restrict__ cand, const u32* __restrict__ gcnt,
    const u32* __restrict__ gT, const u32* __restrict__ boffs,
    u32* __restrict__ bfill, u64* __restrict__ skeys, int cap)
{
  const int b = blockIdx.y;
  u32 cnt = gcnt[b];
  if (cnt > (u32)cap) cnt = (u32)cap;
  const u32 T = gT[b];
  for (u32 i = blockIdx.x * 256 + threadIdx.x; i < cnt; i += gridDim.x * 256) {
    const u64 key = cand[(size_t)b * cap + i];
    const u32 sb = (u32)(key >> 32);
    u32 bk = (sb - BUCK_BASE) >> BUCK_SHIFT;
    if (bk > (u32)(NBUCK - 1)) bk = NBUCK - 1;
    if (bk >= T) {
      const u32 pos = boffs[b * NBUCK + bk] + atomicAdd(&bfill[b * NBUCK + bk], 1u);
      if (pos < (u32)SELCAP) skeys[(size_t)b * SELCAP + pos] = key;
    }
  }
}

// Tiny per-bucket selection sorts complete the descending (score, idx-asc)
// order, then decode the top-2048 into SoA sel_data.
__global__ __launch_bounds__(256) void bsort_decode_kernel(
    u64* __restrict__ skeys, const u32* __restrict__ gT,
    const u32* __restrict__ gTot, const u32* __restrict__ boffs,
    const u32* __restrict__ bfill,
    const float* __restrict__ reg, const float* __restrict__ props,
    float* __restrict__ sel_data)
{
  const int b = blockIdx.x;
  const int tid = threadIdx.x;
  const u32 T = gT[b];
  const u32 totc = gTot[b];
  u64* sk = skeys + (size_t)b * SELCAP;
  for (u32 bk = T + tid; bk < (u32)NBUCK; bk += 256) {
    const u32 start = boffs[b * NBUCK + bk];
    u32 rcnt = bfill[b * NBUCK + bk];
    if (start >= (u32)KSEL || start >= totc) continue;
    if (start + rcnt > totc) rcnt = totc - start;
    if (rcnt < 2) continue;
    u64* run = sk + start;
    for (u32 a = 0; a + 1 < rcnt; ++a) {
      u32 mi = a; u64 mv = run[a];
      for (u32 q = a + 1; q < rcnt; ++q) { const u64 v = run[q]; if (v > mv) { mv = v; mi = q; } }
      if (mi != a) { run[mi] = run[a]; run[a] = mv; }
    }
  }
  __syncthreads();
  float* S = sel_data + (size_t)b * 12 * KSEL;
  for (int t = tid; t < KSEL; t += 256) {
    const u64 key = (t < (int)totc) ? sk[t] : 0ull;
    float x1 = 0, y1 = 0, x2 = 0, y2 = 0, score = 0, lab = 0;
    if (key) {
      const u32 sb = (u32)(key >> 32);
      const u32 idx = ~(u32)key;
      const int n_ = (int)(idx / CM1);
      const int c = (int)(idx % CM1) + 1;
      score = __uint_as_float(sb);
      decode_box(b * Np + n_, c, reg, props, x1, y1, x2, y2);
      lab = (float)c;
    }
    const float offv = __fmul_rn(lab, LBLOFF);
    const float ox1 = __fadd_rn(x1, offv), oy1 = __fadd_rn(y1, offv);
    const float ox2 = __fadd_rn(x2, offv), oy2 = __fadd_rn(y2, offv);
    const float area = __fmul_rn(__fsub_rn(ox2, ox1), __fsub_rn(oy2, oy1));
    S[0*KSEL+t]=x1;  S[1*KSEL+t]=y1;  S[2*KSEL+t]=x2;  S[3*KSEL+t]=y2;
    S[4*KSEL+t]=ox1; S[5*KSEL+t]=oy1; S[6*KSEL+t]=ox2; S[7*KSEL+t]=oy2;
    S[8*KSEL+t]=area; S[9*KSEL+t]=score; S[10*KSEL+t]=lab;
  }
}

// Suppression matrix: one wave per row i, lane j computes iou(i, t*64+j),
// __ballot IS the 64-bit mask word.
__global__ __launch_bounds__(256) void mask_kernel(
    const float* __restrict__ sel_data, u64* __restrict__ mask)
{
  __shared__ float sx1[KSEL], sy1[KSEL], sx2[KSEL], sy2[KSEL], sar[KSEL];
  const int b = blockIdx.y;
  const float* S = sel_data + (size_t)b * 12 * KSEL;
  for (int i = threadIdx.x; i < KSEL; i += 256) {
    sx1[i] = S[4*KSEL+i]; sy1[i] = S[5*KSEL+i];
    sx2[i] = S[6*KSEL+i]; sy2[i] = S[7*KSEL+i];
    sar[i] = S[8*KSEL+i];
  }
  __syncthreads();
  const int wave = threadIdx.x >> 6, lane = threadIdx.x & 63;
  const int i = blockIdx.x * 4 + wave;
  const float ix1 = sx1[i], iy1 = sy1[i], ix2 = sx2[i], iy2 = sy2[i], ia = sar[i];
  u64* mrow = mask + ((size_t)(b * KSEL + i)) * 32;
  for (int t = 0; t < 32; ++t) {
    const int j = (t << 6) + lane;
    const float ltx = fmaxf(ix1, sx1[j]), lty = fmaxf(iy1, sy1[j]);
    const float rbx = fminf(ix2, sx2[j]), rby = fminf(iy2, sy2[j]);
    const float wx = fmaxf(__fsub_rn(rbx, ltx), 0.f);
    const float wy = fmaxf(__fsub_rn(rby, lty), 0.f);
    const float inter = __fmul_rn(wx, wy);
    const float denom = __fadd_rn(__fsub_rn(__fadd_rn(ia, sar[j]), inter), 1e-9f);
    const float iou = __fdiv_rn(inter, denom);
    const u64 word = __ballot(iou > NMS_TH);
    if (lane == 0) mrow[t] = word;
  }
}

// Greedy NMS, early-exit at 100 keeps. Keep-scan iterates only candidate
// bits (todo mask); R-gather stays fixed-trip so the 64 predicated loads
// pipeline under vmcnt.
__global__ __launch_bounds__(64) void nms_out_kernel(
    const float* __restrict__ sel_data, const u64* __restrict__ mask,
    float* __restrict__ out)
{
  const int b = blockIdx.x;
  const int lane = threadIdx.x;
  const float* S = sel_data + (size_t)b * 12 * KSEL;
  __shared__ unsigned short keptIdx[NDET];
  u64 R = 0;   // lanes 0..31 hold the running removed-mask words
  int kc = 0;
  for (int c = 0; c < 32; ++c) {
    const int i = (c << 6) + lane;
    const u64 mword = mask[((size_t)(b * KSEL + i)) * 32 + c];
    const bool valid = S[9 * KSEL + i] > 0.f;
    const u64 vm = __ballot(valid);
    const u64 Rc = shfl64(R, c);
    u64 rem = Rc, keepm = 0;
    u64 todo = vm & ~rem;
    while (todo) {
      const int j = (int)__builtin_ctzll(todo);
      keepm |= 1ull << j;
      const u64 mj = shfl64(mword, j);
      rem |= mj;
      todo &= ~rem;
      todo &= ~(1ull << j);
    }
    if ((keepm >> lane) & 1ull) {
      const int pos = kc + __popcll(keepm & ((1ull << lane) - 1ull));
      if (pos < NDET) keptIdx[pos] = (unsigned short)i;
    }
    kc += __popcll(keepm);
    if (kc >= NDET) break;
    u64 acc = 0;
    if (lane < 32) {
      const u64* mbase = mask + ((size_t)(b * KSEL + (c << 6))) * 32 + lane;
      #pragma unroll
      for (int j = 0; j < 64; ++j)
        if ((keepm >> j) & 1ull) acc |= mbase[(size_t)j * 32];
    }
    R |= acc;
  }
  __syncthreads();
  const int kcl = (kc < NDET) ? kc : NDET;
  for (int k = lane; k < NDET; k += 64) {
    float bx1 = 0, by1 = 0, bx2 = 0, by2 = 0, sc = 0, lb = -1.f;
    if (k < kcl) {
      const int i = keptIdx[k];
      bx1 = S[0*KSEL+i]; by1 = S[1*KSEL+i]; bx2 = S[2*KSEL+i]; by2 = S[3*KSEL+i];
      sc = S[9*KSEL+i];  lb = S[10*KSEL+i];
    }
    float* ob = out + (size_t)b * NDET * 4;
    ob[k*4+0] = bx1; ob[k*4+1] = by1; ob[k*4+2] = bx2; ob[k*4+3] = by2;
    out[Bn*NDET*4 + b*NDET + k] = sc;
    out[Bn*NDET*4 + Bn*NDET + b*NDET + k] = lb;
  }
}

extern "C" void kernel_launch(void* const* d_in, const int* in_sizes, int n_in,
                              void* d_out, int out_size, void* d_ws, size_t ws_size,
                              hipStream_t stream) {
  const float* logits = (const float*)d_in[0];
  const float* reg    = (const float*)d_in[1];
  const float* props  = (const float*)d_in[2];
  float* out = (float*)d_out;
  char* ws = (char*)d_ws;

  u32* gcnt  = (u32*)ws;                       // 2
  u32* gT    = (u32*)(ws + 8);                 // 2
  u32* gTot  = (u32*)(ws + 16);                // 2
  size_t off = 64;
  u32* ghist = (u32*)(ws + off); off += (size_t)Bn * NBUCK * 4;   // 16 KB
  u32* bfill = (u32*)(ws + off); off += (size_t)Bn * NBUCK * 4;   // 16 KB
  const size_t memset_bytes = off;             // zero prefix only
  u32* boffs = (u32*)(ws + off); off += (size_t)Bn * NBUCK * 4;
  off = (off + 255) & ~(size_t)255;
  u64* skeys = (u64*)(ws + off); off += (size_t)Bn * SELCAP * 8;
  float* sel_data = (float*)(ws + off); off += (size_t)Bn * 12 * KSEL * 4;
  off = (off + 255) & ~(size_t)255;
  u64* mask = (u64*)(ws + off); off += (size_t)Bn * KSEL * 32 * 8;
  size_t remain = (ws_size > off) ? (ws_size - off) : 0;
  size_t capz = remain / ((size_t)Bn * 8);
  int cap = (capz > (size_t)(1 << 19)) ? (1 << 19) : (int)capz;
  if (cap < 1) cap = 1;
  u64* cand = (u64*)(ws + off);

  hipMemsetAsync(d_ws, 0, memset_bytes, stream);
  const int waves_per_img = (Np + CHUNK - 1) / CHUNK;          // 3125
  const int blocks_x = (waves_per_img + 3) / 4;                // 782
  pass1_kernel<<<dim3(blocks_x, Bn), 256, 0, stream>>>(logits, reg, props, cand, gcnt, ghist, cap);
  thresh_kernel<<<dim3(Bn), 64, 0, stream>>>(ghist, gT, gTot, boffs);
  scatter_kernel<<<dim3(256, Bn), 256, 0, stream>>>(cand, gcnt, gT, boffs, bfill, skeys, cap);
  bsort_decode_kernel<<<dim3(Bn), 256, 0, stream>>>(skeys, gT, gTot, boffs, bfill, reg, props, sel_data);
  mask_kernel<<<dim3(KSEL / 4, Bn), 256, 0, stream>>>(sel_data, mask);
  nms_out_kernel<<<dim3(Bn), 64, 0, stream>>>(sel_data, mask, out);
}

// Round 4
// 160.193 us; speedup vs baseline: 1.8465x; 1.8119x over previous
//
#include <hip/hip_runtime.h>
#include <hip/hip_bf16.h>
#include <stdint.h>

#define Bn 2
#define Np 50000
#define Cc 81
#define CM1 80
#define KSEL 2048
#define NDET 100
#define NBUCK 2048
#define BUCK_BASE 0x3D000000u
#define BUCK_SHIFT 15
#define SELCAP 4096
#define IMG_W 1333.0f
#define IMG_H 800.0f
#define SCORE_TH 0.05f
#define MIN_SZ 0.01f
#define NMS_TH 0.5f
#define LBLOFF 1401.0f
#define BBOX_CLIP_F 4.135166556742356f
#define CHUNK 16
#define QCAP 320   // >= 16 proposals * 19 max emits

typedef unsigned long long u64;
typedef unsigned int u32;

__device__ __forceinline__ u64 shfl64(u64 v, int src) {
  int lo = __shfl((int)(u32)v, src, 64);
  int hi = __shfl((int)(u32)(v >> 32), src, 64);
  return ((u64)(u32)hi << 32) | (u32)lo;
}

// Torchvision BoxCoder.decode + clip, non-contracted fp32 to match reference.
__device__ __forceinline__ void decode_box(int row, int c,
    const float* __restrict__ reg, const float* __restrict__ props,
    float& x1, float& y1, float& x2, float& y2) {
  const float4 pr = *reinterpret_cast<const float4*>(props + (size_t)row * 4);
  float w = __fsub_rn(pr.z, pr.x), h = __fsub_rn(pr.w, pr.y);
  float cx = __fadd_rn(pr.x, 0.5f * w), cy = __fadd_rn(pr.y, 0.5f * h);
  const float4 rel = *reinterpret_cast<const float4*>(reg + ((size_t)row * Cc + c) * 4);
  float dx = __fdiv_rn(rel.x, 10.f), dy = __fdiv_rn(rel.y, 10.f);
  float dw = fminf(__fdiv_rn(rel.z, 5.f), BBOX_CLIP_F);
  float dh = fminf(__fdiv_rn(rel.w, 5.f), BBOX_CLIP_F);
  float pcx = __fadd_rn(__fmul_rn(dx, w), cx);
  float pcy = __fadd_rn(__fmul_rn(dy, h), cy);
  float pw = __fmul_rn(expf(dw), w);
  float ph = __fmul_rn(expf(dh), h);
  x1 = fminf(fmaxf(__fsub_rn(pcx, 0.5f * pw), 0.f), IMG_W);
  y1 = fminf(fmaxf(__fsub_rn(pcy, 0.5f * ph), 0.f), IMG_H);
  x2 = fminf(fmaxf(__fadd_rn(pcx, 0.5f * pw), 0.f), IMG_W);
  y2 = fminf(fmaxf(__fadd_rn(pcy, 0.5f * ph), 0.f), IMG_H);
}

// Quad-split softmax over one wave's 16-proposal LDS slab. p = lane>>2 owns
// proposal, qd = lane&3 owns 21 classes. Reduce orders are bit-identical to
// the round-3 kernel that matched the reference exactly.
#define SOFTMAX_PROLOG(S)                                            \
  const int p = lane >> 2, qd = lane & 3;                            \
  const int base = p * Cc + qd * 21;                                 \
  const int cnt_k = (qd == 3) ? 18 : 21;                             \
  float ev[21];                                                      \
  _Pragma("unroll")                                                  \
  for (int k = 0; k < 21; ++k)                                       \
    ev[k] = (k < cnt_k) ? (S)[base + k] : -3.4e38f;                  \
  float m = ev[0];                                                   \
  _Pragma("unroll")                                                  \
  for (int k = 1; k < 21; ++k) m = fmaxf(m, ev[k]);                  \
  m = fmaxf(m, __shfl_xor(m, 1, 64));                                \
  m = fmaxf(m, __shfl_xor(m, 2, 64));                                \
  float s = 0.f;                                                     \
  _Pragma("unroll")                                                  \
  for (int k = 0; k < 21; ++k) {                                     \
    ev[k] = (k < cnt_k) ? expf(ev[k] - m) : 0.f;                     \
    s += ev[k];                                                      \
  }                                                                  \
  s += __shfl_xor(s, 1, 64);                                         \
  s += __shfl_xor(s, 2, 64);                                         \
  const float thr = SCORE_TH * s;

// Stage 16 proposals x 81 logits (324 float4, coalesced) into the wave slab.
#define STAGE_LOGITS(S, src)                                         \
  _Pragma("unroll")                                                  \
  for (int i = 0; i < 6; ++i) {                                      \
    const int f4 = i * 64 + lane;                                    \
    if (f4 < (CHUNK * Cc) / 4) {                                     \
      const float4 v = *reinterpret_cast<const float4*>((src) + (size_t)f4 * 4); \
      *reinterpret_cast<float4*>(&(S)[f4 * 4]) = v;                  \
    }                                                                \
  }

// Pass A: softmax -> per-block LDS histogram -> fire-and-forget global
// atomic flush (no return values anywhere; no same-address hot spots).
__global__ __launch_bounds__(256, 4) void passA_kernel(
    const float* __restrict__ logits, u32* __restrict__ ghist)
{
  __shared__ __align__(16) float stg[4][CHUNK * Cc];   // 20736 B
  __shared__ u32 hist[NBUCK];                          // 8192 B
  const int b = blockIdx.y;
  const int tid = threadIdx.x;
  const int wave = tid >> 6, lane = tid & 63;
  for (int i = tid; i < NBUCK; i += 256) hist[i] = 0;
  __syncthreads();
  const int n0 = ((blockIdx.x << 2) + wave) * CHUNK;
  if (n0 < Np) {
    float* S = stg[wave];
    STAGE_LOGITS(S, logits + ((size_t)b * Np + n0) * Cc)
    SOFTMAX_PROLOG(S)
    #pragma unroll
    for (int k = 0; k < 21; ++k) {
      const int c = qd * 21 + k;
      if (c > 0 && ev[k] > thr) {
        const u32 sb = __float_as_uint(__fdiv_rn(ev[k], s));
        u32 bk = (sb - BUCK_BASE) >> BUCK_SHIFT;
        if (bk > (u32)(NBUCK - 1)) bk = NBUCK - 1;
        atomicAdd(&hist[bk], 1u);
      }
    }
  }
  __syncthreads();
  for (int i = tid; i < NBUCK; i += 256) {
    const u32 v = hist[i];
    if (v) atomicAdd(&ghist[b * NBUCK + i], v);   // no return use: fire-and-forget
  }
}

// Per image: T = largest bucket with inclusive suffix >= KSEL (0 if total
// < KSEL); per-bucket exclusive suffix offsets for counting placement.
__global__ void thresh_kernel(const u32* __restrict__ ghist, u32* __restrict__ gT,
                              u32* __restrict__ boffs) {
  const int b = blockIdx.x;
  const int lane = threadIdx.x;  // 64 threads
  const u32* h = ghist + b * NBUCK;
  u32* bo = boffs + b * NBUCK;
  const int SEG = NBUCK / 64;
  u32 segsum = 0;
  for (int t = 0; t < SEG; ++t) segsum += h[lane * SEG + t];
  u32 suf = segsum;
  #pragma unroll
  for (int o = 1; o < 64; o <<= 1) {
    const u32 v = (u32)__shfl_down((int)suf, o, 64);
    if (lane + o < 64) suf += v;
  }
  u32 acc = suf - segsum;   // count in buckets strictly above this segment
  int myT = -1;
  for (int t = SEG - 1; t >= 0; --t) {
    const int bk = lane * SEG + t;
    bo[bk] = acc;
    acc += h[bk];
    if (myT < 0 && acc >= (u32)KSEL) myT = bk;
  }
  int Tg = myT;
  #pragma unroll
  for (int o = 32; o; o >>= 1) Tg = max(Tg, __shfl_xor(Tg, o, 64));
  if (Tg < 0) { if (lane == 0) gT[b] = 0u; }
  else if (myT == Tg) gT[b] = (u32)Tg;
}

// Pass B: recompute softmax; survivors with bucket >= T go to a tiny LDS
// queue; one drain decodes, min-size filters, and places into skeys via
// scattered per-bucket fill atomics (~2 returns per address).
__global__ __launch_bounds__(256, 4) void passB_kernel(
    const float* __restrict__ logits, const float* __restrict__ reg,
    const float* __restrict__ props, const u32* __restrict__ gT,
    const u32* __restrict__ boffs, u32* __restrict__ bfill,
    u64* __restrict__ skeys)
{
  __shared__ __align__(16) float stg[4][CHUNK * Cc];   // 20736 B
  __shared__ u64 qbuf[4][QCAP];                        // 10240 B
  const int b = blockIdx.y;
  const int tid = threadIdx.x;
  const int wave = tid >> 6, lane = tid & 63;
  const int n0 = ((blockIdx.x << 2) + wave) * CHUNK;
  if (n0 >= Np) return;
  const u32 T = gT[b];
  float* S = stg[wave];
  u64* Q = qbuf[wave];
  STAGE_LOGITS(S, logits + ((size_t)b * Np + n0) * Cc)
  SOFTMAX_PROLOG(S)
  const int n_ = n0 + p;
  u32 qcnt = 0;
  #pragma unroll
  for (int k = 0; k < 21; ++k) {
    const int c = qd * 21 + k;
    bool sel = false;
    u64 key = 0;
    if (c > 0 && ev[k] > thr) {
      const u32 sb = __float_as_uint(__fdiv_rn(ev[k], s));
      u32 bk = (sb - BUCK_BASE) >> BUCK_SHIFT;
      if (bk > (u32)(NBUCK - 1)) bk = NBUCK - 1;
      if (bk >= T) {
        const u32 idx = (u32)(n_ * CM1 + (c - 1));
        key = ((u64)sb << 32) | (u32)(~idx);
        sel = true;
      }
    }
    const u64 bal = __ballot(sel);
    if (sel) Q[qcnt + (u32)__popcll(bal & ((1ull << lane) - 1ull))] = key;
    qcnt += (u32)__popcll(bal);
  }
  // drain (rare: ~0.7 survivors per wave on average)
  for (u32 qb = 0; qb < qcnt; qb += 64) {
    const u32 nn = qcnt - qb;
    if (lane < (int)nn) {
      const u64 key = Q[qb + lane];
      const u32 sb = (u32)(key >> 32);
      const u32 idx = ~(u32)key;
      const int pn = (int)(idx / CM1);
      const int c = (int)(idx - (u32)pn * CM1) + 1;
      float x1, y1, x2, y2;
      decode_box(b * Np + pn, c, reg, props, x1, y1, x2, y2);
      if (__fsub_rn(x2, x1) >= MIN_SZ && __fsub_rn(y2, y1) >= MIN_SZ) {
        u32 bk = (sb - BUCK_BASE) >> BUCK_SHIFT;
        if (bk > (u32)(NBUCK - 1)) bk = NBUCK - 1;
        const u32 pos = boffs[b * NBUCK + bk] + atomicAdd(&bfill[b * NBUCK + bk], 1u);
        if (pos < (u32)SELCAP) skeys[(size_t)b * SELCAP + pos] = key;
      }
    }
  }
}

// Full bitonic sort of the <=4096 selected keys (descending; zeros sink),
// then decode top-2048 into SoA sel_data. Run-size-proof.
__global__ __launch_bounds__(1024) void sortdec_kernel(
    const u64* __restrict__ skeys,
    const float* __restrict__ reg, const float* __restrict__ props,
    float* __restrict__ sel_data)
{
  __shared__ u64 keys[SELCAP];
  const int b = blockIdx.x;
  const int tid = threadIdx.x;
  for (int i = tid; i < SELCAP; i += 1024) keys[i] = skeys[(size_t)b * SELCAP + i];
  __syncthreads();
  for (u32 k = 2; k <= (u32)SELCAP; k <<= 1) {
    for (u32 j = k >> 1; j; j >>= 1) {
      for (u32 i = tid; i < (u32)SELCAP; i += 1024) {
        const u32 ix = i ^ j;
        if (ix > i) {
          const u64 a = keys[i], c2 = keys[ix];
          const bool up = ((i & k) == 0);
          if (up ? (a < c2) : (a > c2)) { keys[i] = c2; keys[ix] = a; }
        }
      }
      __syncthreads();
    }
  }
  float* S = sel_data + (size_t)b * 12 * KSEL;
  for (int t = tid; t < KSEL; t += 1024) {
    const u64 key = keys[t];
    float x1 = 0, y1 = 0, x2 = 0, y2 = 0, score = 0, lab = 0;
    if (key) {
      const u32 sb = (u32)(key >> 32);
      const u32 idx = ~(u32)key;
      const int n_ = (int)(idx / CM1);
      const int c = (int)(idx % CM1) + 1;
      score = __uint_as_float(sb);
      decode_box(b * Np + n_, c, reg, props, x1, y1, x2, y2);
      lab = (float)c;
    }
    const float offv = __fmul_rn(lab, LBLOFF);
    const float ox1 = __fadd_rn(x1, offv), oy1 = __fadd_rn(y1, offv);
    const float ox2 = __fadd_rn(x2, offv), oy2 = __fadd_rn(y2, offv);
    const float area = __fmul_rn(__fsub_rn(ox2, ox1), __fsub_rn(oy2, oy1));
    S[0*KSEL+t]=x1;  S[1*KSEL+t]=y1;  S[2*KSEL+t]=x2;  S[3*KSEL+t]=y2;
    S[4*KSEL+t]=ox1; S[5*KSEL+t]=oy1; S[6*KSEL+t]=ox2; S[7*KSEL+t]=oy2;
    S[8*KSEL+t]=area; S[9*KSEL+t]=score; S[10*KSEL+t]=lab;
  }
}

// Suppression matrix: one wave per row i, lane j computes iou(i, t*64+j),
// __ballot IS the 64-bit mask word.
__global__ __launch_bounds__(256) void mask_kernel(
    const float* __restrict__ sel_data, u64* __restrict__ mask)
{
  __shared__ float sx1[KSEL], sy1[KSEL], sx2[KSEL], sy2[KSEL], sar[KSEL];
  const int b = blockIdx.y;
  const float* S = sel_data + (size_t)b * 12 * KSEL;
  for (int i = threadIdx.x; i < KSEL; i += 256) {
    sx1[i] = S[4*KSEL+i]; sy1[i] = S[5*KSEL+i];
    sx2[i] = S[6*KSEL+i]; sy2[i] = S[7*KSEL+i];
    sar[i] = S[8*KSEL+i];
  }
  __syncthreads();
  const int wave = threadIdx.x >> 6, lane = threadIdx.x & 63;
  const int i = blockIdx.x * 4 + wave;
  const float ix1 = sx1[i], iy1 = sy1[i], ix2 = sx2[i], iy2 = sy2[i], ia = sar[i];
  u64* mrow = mask + ((size_t)(b * KSEL + i)) * 32;
  for (int t = 0; t < 32; ++t) {
    const int j = (t << 6) + lane;
    const float ltx = fmaxf(ix1, sx1[j]), lty = fmaxf(iy1, sy1[j]);
    const float rbx = fminf(ix2, sx2[j]), rby = fminf(iy2, sy2[j]);
    const float wx = fmaxf(__fsub_rn(rbx, ltx), 0.f);
    const float wy = fmaxf(__fsub_rn(rby, lty), 0.f);
    const float inter = __fmul_rn(wx, wy);
    const float denom = __fadd_rn(__fsub_rn(__fadd_rn(ia, sar[j]), inter), 1e-9f);
    const float iou = __fdiv_rn(inter, denom);
    const u64 word = __ballot(iou > NMS_TH);
    if (lane == 0) mrow[t] = word;
  }
}

// Greedy NMS, early-exit at 100 keeps.
__global__ __launch_bounds__(64) void nms_out_kernel(
    const float* __restrict__ sel_data, const u64* __restrict__ mask,
    float* __restrict__ out)
{
  const int b = blockIdx.x;
  const int lane = threadIdx.x;
  const float* S = sel_data + (size_t)b * 12 * KSEL;
  __shared__ unsigned short keptIdx[NDET];
  u64 R = 0;   // lanes 0..31 hold the running removed-mask words
  int kc = 0;
  for (int c = 0; c < 32; ++c) {
    const int i = (c << 6) + lane;
    const u64 mword = mask[((size_t)(b * KSEL + i)) * 32 + c];
    const bool valid = S[9 * KSEL + i] > 0.f;
    const u64 vm = __ballot(valid);
    const u64 Rc = shfl64(R, c);
    u64 rem = Rc, keepm = 0;
    u64 todo = vm & ~rem;
    while (todo) {
      const int j = (int)__builtin_ctzll(todo);
      keepm |= 1ull << j;
      const u64 mj = shfl64(mword, j);
      rem |= mj;
      todo &= ~rem;
      todo &= ~(1ull << j);
    }
    if ((keepm >> lane) & 1ull) {
      const int pos = kc + __popcll(keepm & ((1ull << lane) - 1ull));
      if (pos < NDET) keptIdx[pos] = (unsigned short)i;
    }
    kc += __popcll(keepm);
    if (kc >= NDET) break;
    u64 acc = 0;
    if (lane < 32) {
      const u64* mbase = mask + ((size_t)(b * KSEL + (c << 6))) * 32 + lane;
      #pragma unroll
      for (int j = 0; j < 64; ++j)
        if ((keepm >> j) & 1ull) acc |= mbase[(size_t)j * 32];
    }
    R |= acc;
  }
  __syncthreads();
  const int kcl = (kc < NDET) ? kc : NDET;
  for (int k = lane; k < NDET; k += 64) {
    float bx1 = 0, by1 = 0, bx2 = 0, by2 = 0, sc = 0, lb = -1.f;
    if (k < kcl) {
      const int i = keptIdx[k];
      bx1 = S[0*KSEL+i]; by1 = S[1*KSEL+i]; bx2 = S[2*KSEL+i]; by2 = S[3*KSEL+i];
      sc = S[9*KSEL+i];  lb = S[10*KSEL+i];
    }
    float* ob = out + (size_t)b * NDET * 4;
    ob[k*4+0] = bx1; ob[k*4+1] = by1; ob[k*4+2] = bx2; ob[k*4+3] = by2;
    out[Bn*NDET*4 + b*NDET + k] = sc;
    out[Bn*NDET*4 + Bn*NDET + b*NDET + k] = lb;
  }
}

extern "C" void kernel_launch(void* const* d_in, const int* in_sizes, int n_in,
                              void* d_out, int out_size, void* d_ws, size_t ws_size,
                              hipStream_t stream) {
  const float* logits = (const float*)d_in[0];
  const float* reg    = (const float*)d_in[1];
  const float* props  = (const float*)d_in[2];
  float* out = (float*)d_out;
  char* ws = (char*)d_ws;

  // Layout: [header | ghist | bfill | skeys]  <- memset to 0 each call
  //         [boffs | sel_data | mask]         <- fully overwritten each call
  u32* gT = (u32*)ws;                          // 2 u32
  size_t off = 64;
  u32* ghist = (u32*)(ws + off); off += (size_t)Bn * NBUCK * 4;   // 16 KB
  u32* bfill = (u32*)(ws + off); off += (size_t)Bn * NBUCK * 4;   // 16 KB
  u64* skeys = (u64*)(ws + off); off += (size_t)Bn * SELCAP * 8;  // 64 KB
  const size_t memset_bytes = off;
  u32* boffs = (u32*)(ws + off); off += (size_t)Bn * NBUCK * 4;   // 16 KB
  float* sel_data = (float*)(ws + off); off += (size_t)Bn * 12 * KSEL * 4;
  off = (off + 255) & ~(size_t)255;
  u64* mask = (u64*)(ws + off); off += (size_t)Bn * KSEL * 32 * 8;
  (void)ws_size;

  hipMemsetAsync(d_ws, 0, memset_bytes, stream);
  const int blocks_x = (Np + 4 * CHUNK - 1) / (4 * CHUNK);   // 782
  passA_kernel<<<dim3(blocks_x, Bn), 256, 0, stream>>>(logits, ghist);
  thresh_kernel<<<dim3(Bn), 64, 0, stream>>>(ghist, gT, boffs);
  passB_kernel<<<dim3(blocks_x, Bn), 256, 0, stream>>>(logits, reg, props, gT, boffs, bfill, skeys);
  sortdec_kernel<<<dim3(Bn), 1024, 0, stream>>>(skeys, reg, props, sel_data);
  mask_kernel<<<dim3(KSEL / 4, Bn), 256, 0, stream>>>(sel_data, mask);
  nms_out_kernel<<<dim3(Bn), 64, 0, stream>>>(sel_data, mask, out);
}

// Round 5
// 135.327 us; speedup vs baseline: 2.1858x; 1.1837x over previous
//
#include <hip/hip_runtime.h>
#include <hip/hip_bf16.h>
#include <stdint.h>

#define Bn 2
#define Np 50000
#define Cc 81
#define CM1 80
#define KSEL 2048
#define NDET 100
#define NBUCK 2048
#define BUCK_BASE 0x3D000000u
#define BUCK_SHIFT 15
#define SELCAP 4096
#define IMG_W 1333.0f
#define IMG_H 800.0f
#define SCORE_TH 0.05f
#define MIN_SZ 0.01f
#define NMS_TH 0.5f
#define LBLOFF 1401.0f
#define BBOX_CLIP_F 4.135166556742356f
#define CHUNK 16
#define QCAP 320   // >= 16 proposals * 19 max emits

typedef unsigned long long u64;
typedef unsigned int u32;

// Torchvision BoxCoder.decode + clip, non-contracted fp32 to match reference.
__device__ __forceinline__ void decode_box(int row, int c,
    const float* __restrict__ reg, const float* __restrict__ props,
    float& x1, float& y1, float& x2, float& y2) {
  const float4 pr = *reinterpret_cast<const float4*>(props + (size_t)row * 4);
  float w = __fsub_rn(pr.z, pr.x), h = __fsub_rn(pr.w, pr.y);
  float cx = __fadd_rn(pr.x, 0.5f * w), cy = __fadd_rn(pr.y, 0.5f * h);
  const float4 rel = *reinterpret_cast<const float4*>(reg + ((size_t)row * Cc + c) * 4);
  float dx = __fdiv_rn(rel.x, 10.f), dy = __fdiv_rn(rel.y, 10.f);
  float dw = fminf(__fdiv_rn(rel.z, 5.f), BBOX_CLIP_F);
  float dh = fminf(__fdiv_rn(rel.w, 5.f), BBOX_CLIP_F);
  float pcx = __fadd_rn(__fmul_rn(dx, w), cx);
  float pcy = __fadd_rn(__fmul_rn(dy, h), cy);
  float pw = __fmul_rn(expf(dw), w);
  float ph = __fmul_rn(expf(dh), h);
  x1 = fminf(fmaxf(__fsub_rn(pcx, 0.5f * pw), 0.f), IMG_W);
  y1 = fminf(fmaxf(__fsub_rn(pcy, 0.5f * ph), 0.f), IMG_H);
  x2 = fminf(fmaxf(__fadd_rn(pcx, 0.5f * pw), 0.f), IMG_W);
  y2 = fminf(fmaxf(__fadd_rn(pcy, 0.5f * ph), 0.f), IMG_H);
}

// Quad-split softmax over one wave's 16-proposal LDS slab. p = lane>>2 owns
// proposal, qd = lane&3 owns 21 classes. Reduce orders are bit-identical to
// the round-3/4 kernels that matched the reference exactly.
#define SOFTMAX_PROLOG(S)                                            \
  const int p = lane >> 2, qd = lane & 3;                            \
  const int base = p * Cc + qd * 21;                                 \
  const int cnt_k = (qd == 3) ? 18 : 21;                             \
  float ev[21];                                                      \
  _Pragma("unroll")                                                  \
  for (int k = 0; k < 21; ++k)                                       \
    ev[k] = (k < cnt_k) ? (S)[base + k] : -3.4e38f;                  \
  float m = ev[0];                                                   \
  _Pragma("unroll")                                                  \
  for (int k = 1; k < 21; ++k) m = fmaxf(m, ev[k]);                  \
  m = fmaxf(m, __shfl_xor(m, 1, 64));                                \
  m = fmaxf(m, __shfl_xor(m, 2, 64));                                \
  float s = 0.f;                                                     \
  _Pragma("unroll")                                                  \
  for (int k = 0; k < 21; ++k) {                                     \
    ev[k] = (k < cnt_k) ? expf(ev[k] - m) : 0.f;                     \
    s += ev[k];                                                      \
  }                                                                  \
  s += __shfl_xor(s, 1, 64);                                         \
  s += __shfl_xor(s, 2, 64);                                         \
  const float thr = SCORE_TH * s;

// Stage 16 proposals x 81 logits (324 float4, coalesced) into the wave slab.
#define STAGE_LOGITS(S, src)                                         \
  _Pragma("unroll")                                                  \
  for (int i = 0; i < 6; ++i) {                                      \
    const int f4 = i * 64 + lane;                                    \
    if (f4 < (CHUNK * Cc) / 4) {                                     \
      const float4 v = *reinterpret_cast<const float4*>((src) + (size_t)f4 * 4); \
      *reinterpret_cast<float4*>(&(S)[f4 * 4]) = v;                  \
    }                                                                \
  }

// Pass A: softmax -> per-block LDS histogram -> fire-and-forget global
// atomic flush (no return values; no same-address hot spots).
__global__ __launch_bounds__(256, 4) void passA_kernel(
    const float* __restrict__ logits, u32* __restrict__ ghist)
{
  __shared__ __align__(16) float stg[4][CHUNK * Cc];   // 20736 B
  __shared__ u32 hist[NBUCK];                          // 8192 B
  const int b = blockIdx.y;
  const int tid = threadIdx.x;
  const int wave = tid >> 6, lane = tid & 63;
  for (int i = tid; i < NBUCK; i += 256) hist[i] = 0;
  __syncthreads();
  const int n0 = ((blockIdx.x << 2) + wave) * CHUNK;
  if (n0 < Np) {
    float* S = stg[wave];
    STAGE_LOGITS(S, logits + ((size_t)b * Np + n0) * Cc)
    SOFTMAX_PROLOG(S)
    #pragma unroll
    for (int k = 0; k < 21; ++k) {
      const int c = qd * 21 + k;
      if (c > 0 && ev[k] > thr) {
        const u32 sb = __float_as_uint(__fdiv_rn(ev[k], s));
        u32 bk = (sb - BUCK_BASE) >> BUCK_SHIFT;
        if (bk > (u32)(NBUCK - 1)) bk = NBUCK - 1;
        atomicAdd(&hist[bk], 1u);
      }
    }
  }
  __syncthreads();
  for (int i = tid; i < NBUCK; i += 256) {
    const u32 v = hist[i];
    if (v) atomicAdd(&ghist[b * NBUCK + i], v);   // no return use: fire-and-forget
  }
}

// Per image: T = largest bucket with inclusive suffix >= KSEL (0 if total
// < KSEL); per-bucket exclusive suffix offsets for counting placement.
__global__ void thresh_kernel(const u32* __restrict__ ghist, u32* __restrict__ gT,
                              u32* __restrict__ boffs) {
  const int b = blockIdx.x;
  const int lane = threadIdx.x;  // 64 threads
  const u32* h = ghist + b * NBUCK;
  u32* bo = boffs + b * NBUCK;
  const int SEG = NBUCK / 64;
  u32 segsum = 0;
  for (int t = 0; t < SEG; ++t) segsum += h[lane * SEG + t];
  u32 suf = segsum;
  #pragma unroll
  for (int o = 1; o < 64; o <<= 1) {
    const u32 v = (u32)__shfl_down((int)suf, o, 64);
    if (lane + o < 64) suf += v;
  }
  u32 acc = suf - segsum;   // count in buckets strictly above this segment
  int myT = -1;
  for (int t = SEG - 1; t >= 0; --t) {
    const int bk = lane * SEG + t;
    bo[bk] = acc;
    acc += h[bk];
    if (myT < 0 && acc >= (u32)KSEL) myT = bk;
  }
  int Tg = myT;
  #pragma unroll
  for (int o = 32; o; o >>= 1) Tg = max(Tg, __shfl_xor(Tg, o, 64));
  if (Tg < 0) { if (lane == 0) gT[b] = 0u; }
  else if (myT == Tg) gT[b] = (u32)Tg;
}

// Pass B: recompute softmax; survivors with bucket >= T go to a tiny LDS
// queue; one drain decodes, min-size filters, and places into skeys via
// scattered per-bucket fill atomics (~2 returns per address).
__global__ __launch_bounds__(256, 4) void passB_kernel(
    const float* __restrict__ logits, const float* __restrict__ reg,
    const float* __restrict__ props, const u32* __restrict__ gT,
    const u32* __restrict__ boffs, u32* __restrict__ bfill,
    u64* __restrict__ skeys)
{
  __shared__ __align__(16) float stg[4][CHUNK * Cc];   // 20736 B
  __shared__ u64 qbuf[4][QCAP];                        // 10240 B
  const int b = blockIdx.y;
  const int tid = threadIdx.x;
  const int wave = tid >> 6, lane = tid & 63;
  const int n0 = ((blockIdx.x << 2) + wave) * CHUNK;
  if (n0 >= Np) return;
  const u32 T = gT[b];
  float* S = stg[wave];
  u64* Q = qbuf[wave];
  STAGE_LOGITS(S, logits + ((size_t)b * Np + n0) * Cc)
  SOFTMAX_PROLOG(S)
  const int n_ = n0 + p;
  u32 qcnt = 0;
  #pragma unroll
  for (int k = 0; k < 21; ++k) {
    const int c = qd * 21 + k;
    bool sel = false;
    u64 key = 0;
    if (c > 0 && ev[k] > thr) {
      const u32 sb = __float_as_uint(__fdiv_rn(ev[k], s));
      u32 bk = (sb - BUCK_BASE) >> BUCK_SHIFT;
      if (bk > (u32)(NBUCK - 1)) bk = NBUCK - 1;
      if (bk >= T) {
        const u32 idx = (u32)(n_ * CM1 + (c - 1));
        key = ((u64)sb << 32) | (u32)(~idx);
        sel = true;
      }
    }
    const u64 bal = __ballot(sel);
    if (sel) Q[qcnt + (u32)__popcll(bal & ((1ull << lane) - 1ull))] = key;
    qcnt += (u32)__popcll(bal);
  }
  // drain (rare: ~0.7 survivors per wave on average)
  for (u32 qb = 0; qb < qcnt; qb += 64) {
    const u32 nn = qcnt - qb;
    if (lane < (int)nn) {
      const u64 key = Q[qb + lane];
      const u32 sb = (u32)(key >> 32);
      const u32 idx = ~(u32)key;
      const int pn = (int)(idx / CM1);
      const int c = (int)(idx - (u32)pn * CM1) + 1;
      float x1, y1, x2, y2;
      decode_box(b * Np + pn, c, reg, props, x1, y1, x2, y2);
      if (__fsub_rn(x2, x1) >= MIN_SZ && __fsub_rn(y2, y1) >= MIN_SZ) {
        u32 bk = (sb - BUCK_BASE) >> BUCK_SHIFT;
        if (bk > (u32)(NBUCK - 1)) bk = NBUCK - 1;
        const u32 pos = boffs[b * NBUCK + bk] + atomicAdd(&bfill[b * NBUCK + bk], 1u);
        if (pos < (u32)SELCAP) skeys[(size_t)b * SELCAP + pos] = key;
      }
    }
  }
}

// Fused tail: bitonic-sort 4096 keys in LDS -> decode offset boxes/areas/
// scores into LDS -> greedy NMS with on-the-fly IoU vs the kept list
// (early-exit at 100 keeps; only ~2-3 of 32 chunks are ever examined) ->
// decode + write the <=100 outputs. One block per image.
__global__ __launch_bounds__(1024) void tail_kernel(
    const u64* __restrict__ skeys,
    const float* __restrict__ reg, const float* __restrict__ props,
    float* __restrict__ out)
{
  __shared__ u64 keys[SELCAP];                                   // 32 KB
  __shared__ float obx1[KSEL], oby1[KSEL], obx2[KSEL], oby2[KSEL];
  __shared__ float oar[KSEL], osc[KSEL];                         // 48 KB
  __shared__ unsigned short keptIdx[NDET];
  __shared__ u32 supflags[64];
  __shared__ u32 sh_kc;
  const int b = blockIdx.x;
  const int tid = threadIdx.x;
  const int wave = tid >> 6, lane = tid & 63;

  for (int i = tid; i < SELCAP; i += 1024) keys[i] = skeys[(size_t)b * SELCAP + i];
  if (tid == 0) sh_kc = 0;
  __syncthreads();

  // Bitonic sort, descending (zero keys sink to the end). Total order on
  // (score bits, ~idx) == reference's (score desc, idx asc).
  for (u32 k = 2; k <= (u32)SELCAP; k <<= 1) {
    for (u32 j = k >> 1; j; j >>= 1) {
      for (u32 i = tid; i < (u32)SELCAP; i += 1024) {
        const u32 ix = i ^ j;
        if (ix > i) {
          const u64 a = keys[i], c2 = keys[ix];
          const bool up = ((i & k) == 0);
          if (up ? (a < c2) : (a > c2)) { keys[i] = c2; keys[ix] = a; }
        }
      }
      __syncthreads();
    }
  }

  // Decode top-2048 into LDS (class-offset box + area + score).
  for (int t = tid; t < KSEL; t += 1024) {
    const u64 key = keys[t];
    float x1 = 0, y1 = 0, x2 = 0, y2 = 0, score = 0, lab = 0;
    if (key) {
      const u32 sb = (u32)(key >> 32);
      const u32 idx = ~(u32)key;
      const int n_ = (int)(idx / CM1);
      const int c = (int)(idx % CM1) + 1;
      score = __uint_as_float(sb);
      decode_box(b * Np + n_, c, reg, props, x1, y1, x2, y2);
      lab = (float)c;
    }
    const float offv = __fmul_rn(lab, LBLOFF);
    const float ox1 = __fadd_rn(x1, offv), oy1 = __fadd_rn(y1, offv);
    const float ox2 = __fadd_rn(x2, offv), oy2 = __fadd_rn(y2, offv);
    obx1[t] = ox1; oby1[t] = oy1; obx2[t] = ox2; oby2[t] = oy2;
    oar[t] = __fmul_rn(__fsub_rn(ox2, ox1), __fsub_rn(oy2, oy1));
    osc[t] = score;
  }
  __syncthreads();

  // Greedy NMS.
  int kc = 0;
  for (int c = 0; c < 32 && kc < NDET; ++c) {
    if (tid < 64) supflags[tid] = 0;
    __syncthreads();
    // Phase 1 (all 16 waves): candidate j vs kept[k], k strided by wave.
    const int j = (c << 6) + lane;
    const float cx1 = obx1[j], cy1 = oby1[j], cx2 = obx2[j], cy2 = oby2[j], ca = oar[j];
    bool sup = false;
    for (int k = wave; k < kc; k += 16) {
      const int ki = keptIdx[k];
      const float ltx = fmaxf(cx1, obx1[ki]), lty = fmaxf(cy1, oby1[ki]);
      const float rbx = fminf(cx2, obx2[ki]), rby = fminf(cy2, oby2[ki]);
      const float wx = fmaxf(__fsub_rn(rbx, ltx), 0.f);
      const float wy = fmaxf(__fsub_rn(rby, lty), 0.f);
      const float inter = __fmul_rn(wx, wy);
      const float denom = __fadd_rn(__fsub_rn(__fadd_rn(ca, oar[ki]), inter), 1e-9f);
      if (__fdiv_rn(inter, denom) > NMS_TH) sup = true;
    }
    if (sup) supflags[lane] = 1u;   // benign same-value race
    __syncthreads();
    // Phase 2 (wave 0): sequential within-chunk resolve with per-lane IoU.
    if (wave == 0) {
      u64 rem = __ballot(supflags[lane] != 0u);
      u64 todo = __ballot(osc[j] > 0.f) & ~rem;
      int kcl = kc;
      while (todo && kcl < NDET) {
        const int jb = (int)__builtin_ctzll(todo);
        const int cj = (c << 6) + jb;
        if (lane == 0) keptIdx[kcl] = (unsigned short)cj;
        ++kcl;
        const float kx1 = obx1[cj], ky1 = oby1[cj], kx2 = obx2[cj], ky2 = oby2[cj], ka = oar[cj];
        const float ltx = fmaxf(kx1, cx1), lty = fmaxf(ky1, cy1);
        const float rbx = fminf(kx2, cx2), rby = fminf(ky2, cy2);
        const float wx = fmaxf(__fsub_rn(rbx, ltx), 0.f);
        const float wy = fmaxf(__fsub_rn(rby, lty), 0.f);
        const float inter = __fmul_rn(wx, wy);
        const float denom = __fadd_rn(__fsub_rn(__fadd_rn(ka, ca), inter), 1e-9f);
        const u64 w = __ballot(__fdiv_rn(inter, denom) > NMS_TH);
        rem |= w;
        todo &= ~rem;
        todo &= ~(1ull << jb);
      }
      if (lane == 0) sh_kc = (u32)kcl;
    }
    __syncthreads();
    kc = (int)sh_kc;
  }

  // Output: first min(kc,100) kept, padded with zeros / label -1.
  __syncthreads();
  const int kcl = (kc < NDET) ? kc : NDET;
  if (tid < NDET) {
    float bx1 = 0, by1 = 0, bx2 = 0, by2 = 0, sc = 0, lb = -1.f;
    if (tid < kcl) {
      const int i = keptIdx[tid];
      const u64 key = keys[i];
      const u32 idx = ~(u32)key;
      const int n_ = (int)(idx / CM1);
      const int cc = (int)(idx % CM1) + 1;
      decode_box(b * Np + n_, cc, reg, props, bx1, by1, bx2, by2);
      sc = osc[i];
      lb = (float)cc;
    }
    float* ob = out + (size_t)b * NDET * 4;
    ob[tid * 4 + 0] = bx1; ob[tid * 4 + 1] = by1;
    ob[tid * 4 + 2] = bx2; ob[tid * 4 + 3] = by2;
    out[Bn * NDET * 4 + b * NDET + tid] = sc;
    out[Bn * NDET * 4 + Bn * NDET + b * NDET + tid] = lb;
  }
}

extern "C" void kernel_launch(void* const* d_in, const int* in_sizes, int n_in,
                              void* d_out, int out_size, void* d_ws, size_t ws_size,
                              hipStream_t stream) {
  const float* logits = (const float*)d_in[0];
  const float* reg    = (const float*)d_in[1];
  const float* props  = (const float*)d_in[2];
  float* out = (float*)d_out;
  char* ws = (char*)d_ws;

  // Layout: [header | ghist | bfill | skeys]  <- memset to 0 each call
  //         [boffs]                           <- fully overwritten each call
  u32* gT = (u32*)ws;                          // 2 u32
  size_t off = 64;
  u32* ghist = (u32*)(ws + off); off += (size_t)Bn * NBUCK * 4;   // 16 KB
  u32* bfill = (u32*)(ws + off); off += (size_t)Bn * NBUCK * 4;   // 16 KB
  u64* skeys = (u64*)(ws + off); off += (size_t)Bn * SELCAP * 8;  // 64 KB
  const size_t memset_bytes = off;
  u32* boffs = (u32*)(ws + off); off += (size_t)Bn * NBUCK * 4;   // 16 KB
  (void)ws_size;

  hipMemsetAsync(d_ws, 0, memset_bytes, stream);
  const int blocks_x = (Np + 4 * CHUNK - 1) / (4 * CHUNK);   // 782
  passA_kernel<<<dim3(blocks_x, Bn), 256, 0, stream>>>(logits, ghist);
  thresh_kernel<<<dim3(Bn), 64, 0, stream>>>(ghist, gT, boffs);
  passB_kernel<<<dim3(blocks_x, Bn), 256, 0, stream>>>(logits, reg, props, gT, boffs, bfill, skeys);
  tail_kernel<<<dim3(Bn), 1024, 0, stream>>>(skeys, reg, props, out);
}

// Round 6
// 88.133 us; speedup vs baseline: 3.3563x; 1.5355x over previous
//
#include <hip/hip_runtime.h>
#include <hip/hip_bf16.h>
#include <stdint.h>

#define Bn 2
#define Np 50000
#define Cc 81
#define CM1 80
#define KSEL 2048
#define NDET 100
#define NBUCK 2048
#define BUCK_BASE 0x3D000000u
#define BUCK_SHIFT 15
#define SELCAP 4096
#define IMG_W 1333.0f
#define IMG_H 800.0f
#define SCORE_TH 0.05f
#define MIN_SZ 0.01f
#define NMS_TH 0.5f
#define LBLOFF 1401.0f
#define BBOX_CLIP_F 4.135166556742356f
#define CHUNK 16
#define QCAP 320   // >= 16 proposals * 19 max emits
#define RS_WPB 4   // runsort waves per block

typedef unsigned long long u64;
typedef unsigned int u32;

__device__ __forceinline__ u64 shfl64(u64 v, int src) {
  int lo = __shfl((int)(u32)v, src, 64);
  int hi = __shfl((int)(u32)(v >> 32), src, 64);
  return ((u64)(u32)hi << 32) | (u32)lo;
}

// Torchvision BoxCoder.decode + clip, non-contracted fp32 to match reference.
__device__ __forceinline__ void decode_box(int row, int c,
    const float* __restrict__ reg, const float* __restrict__ props,
    float& x1, float& y1, float& x2, float& y2) {
  const float4 pr = *reinterpret_cast<const float4*>(props + (size_t)row * 4);
  float w = __fsub_rn(pr.z, pr.x), h = __fsub_rn(pr.w, pr.y);
  float cx = __fadd_rn(pr.x, 0.5f * w), cy = __fadd_rn(pr.y, 0.5f * h);
  const float4 rel = *reinterpret_cast<const float4*>(reg + ((size_t)row * Cc + c) * 4);
  float dx = __fdiv_rn(rel.x, 10.f), dy = __fdiv_rn(rel.y, 10.f);
  float dw = fminf(__fdiv_rn(rel.z, 5.f), BBOX_CLIP_F);
  float dh = fminf(__fdiv_rn(rel.w, 5.f), BBOX_CLIP_F);
  float pcx = __fadd_rn(__fmul_rn(dx, w), cx);
  float pcy = __fadd_rn(__fmul_rn(dy, h), cy);
  float pw = __fmul_rn(expf(dw), w);
  float ph = __fmul_rn(expf(dh), h);
  x1 = fminf(fmaxf(__fsub_rn(pcx, 0.5f * pw), 0.f), IMG_W);
  y1 = fminf(fmaxf(__fsub_rn(pcy, 0.5f * ph), 0.f), IMG_H);
  x2 = fminf(fmaxf(__fadd_rn(pcx, 0.5f * pw), 0.f), IMG_W);
  y2 = fminf(fmaxf(__fadd_rn(pcy, 0.5f * ph), 0.f), IMG_H);
}

// Quad-split softmax over one wave's 16-proposal LDS slab. p = lane>>2 owns
// proposal, qd = lane&3 owns 21 classes. Reduce orders are bit-identical to
// the round-3/4/5 kernels that matched the reference exactly.
#define SOFTMAX_PROLOG(S)                                            \
  const int p = lane >> 2, qd = lane & 3;                            \
  const int base = p * Cc + qd * 21;                                 \
  const int cnt_k = (qd == 3) ? 18 : 21;                             \
  float ev[21];                                                      \
  _Pragma("unroll")                                                  \
  for (int k = 0; k < 21; ++k)                                       \
    ev[k] = (k < cnt_k) ? (S)[base + k] : -3.4e38f;                  \
  float m = ev[0];                                                   \
  _Pragma("unroll")                                                  \
  for (int k = 1; k < 21; ++k) m = fmaxf(m, ev[k]);                  \
  m = fmaxf(m, __shfl_xor(m, 1, 64));                                \
  m = fmaxf(m, __shfl_xor(m, 2, 64));                                \
  float s = 0.f;                                                     \
  _Pragma("unroll")                                                  \
  for (int k = 0; k < 21; ++k) {                                     \
    ev[k] = (k < cnt_k) ? expf(ev[k] - m) : 0.f;                     \
    s += ev[k];                                                      \
  }                                                                  \
  s += __shfl_xor(s, 1, 64);                                         \
  s += __shfl_xor(s, 2, 64);                                         \
  const float thr = SCORE_TH * s;

// Stage 16 proposals x 81 logits (324 float4, coalesced) into the wave slab.
#define STAGE_LOGITS(S, src)                                         \
  _Pragma("unroll")                                                  \
  for (int i = 0; i < 6; ++i) {                                      \
    const int f4 = i * 64 + lane;                                    \
    if (f4 < (CHUNK * Cc) / 4) {                                     \
      const float4 v = *reinterpret_cast<const float4*>((src) + (size_t)f4 * 4); \
      *reinterpret_cast<float4*>(&(S)[f4 * 4]) = v;                  \
    }                                                                \
  }

// Pass A: softmax -> per-block LDS histogram -> fire-and-forget global
// atomic flush (no return values; no same-address hot spots).
__global__ __launch_bounds__(256, 4) void passA_kernel(
    const float* __restrict__ logits, u32* __restrict__ ghist)
{
  __shared__ __align__(16) float stg[4][CHUNK * Cc];   // 20736 B
  __shared__ u32 hist[NBUCK];                          // 8192 B
  const int b = blockIdx.y;
  const int tid = threadIdx.x;
  const int wave = tid >> 6, lane = tid & 63;
  for (int i = tid; i < NBUCK; i += 256) hist[i] = 0;
  __syncthreads();
  const int n0 = ((blockIdx.x << 2) + wave) * CHUNK;
  if (n0 < Np) {
    float* S = stg[wave];
    STAGE_LOGITS(S, logits + ((size_t)b * Np + n0) * Cc)
    SOFTMAX_PROLOG(S)
    #pragma unroll
    for (int k = 0; k < 21; ++k) {
      const int c = qd * 21 + k;
      if (c > 0 && ev[k] > thr) {
        const u32 sb = __float_as_uint(__fdiv_rn(ev[k], s));
        u32 bk = (sb - BUCK_BASE) >> BUCK_SHIFT;
        if (bk > (u32)(NBUCK - 1)) bk = NBUCK - 1;
        atomicAdd(&hist[bk], 1u);
      }
    }
  }
  __syncthreads();
  for (int i = tid; i < NBUCK; i += 256) {
    const u32 v = hist[i];
    if (v) atomicAdd(&ghist[b * NBUCK + i], v);   // no return use: fire-and-forget
  }
}

// Per image: T = largest bucket with inclusive suffix >= KSEL (0 if total
// < KSEL); per-bucket exclusive suffix offsets for counting placement.
__global__ void thresh_kernel(const u32* __restrict__ ghist, u32* __restrict__ gT,
                              u32* __restrict__ boffs) {
  const int b = blockIdx.x;
  const int lane = threadIdx.x;  // 64 threads
  const u32* h = ghist + b * NBUCK;
  u32* bo = boffs + b * NBUCK;
  const int SEG = NBUCK / 64;
  u32 segsum = 0;
  for (int t = 0; t < SEG; ++t) segsum += h[lane * SEG + t];
  u32 suf = segsum;
  #pragma unroll
  for (int o = 1; o < 64; o <<= 1) {
    const u32 v = (u32)__shfl_down((int)suf, o, 64);
    if (lane + o < 64) suf += v;
  }
  u32 acc = suf - segsum;   // count in buckets strictly above this segment
  int myT = -1;
  for (int t = SEG - 1; t >= 0; --t) {
    const int bk = lane * SEG + t;
    bo[bk] = acc;
    acc += h[bk];
    if (myT < 0 && acc >= (u32)KSEL) myT = bk;
  }
  int Tg = myT;
  #pragma unroll
  for (int o = 32; o; o >>= 1) Tg = max(Tg, __shfl_xor(Tg, o, 64));
  if (Tg < 0) { if (lane == 0) gT[b] = 0u; }
  else if (myT == Tg) gT[b] = (u32)Tg;
}

// Pass B: recompute softmax; survivors with bucket >= T go to a tiny LDS
// queue; one drain decodes, min-size filters, and places into skeys via
// scattered per-bucket fill atomics (~2 returns per address).
__global__ __launch_bounds__(256, 4) void passB_kernel(
    const float* __restrict__ logits, const float* __restrict__ reg,
    const float* __restrict__ props, const u32* __restrict__ gT,
    const u32* __restrict__ boffs, u32* __restrict__ bfill,
    u64* __restrict__ skeys)
{
  __shared__ __align__(16) float stg[4][CHUNK * Cc];   // 20736 B
  __shared__ u64 qbuf[4][QCAP];                        // 10240 B
  const int b = blockIdx.y;
  const int tid = threadIdx.x;
  const int wave = tid >> 6, lane = tid & 63;
  const int n0 = ((blockIdx.x << 2) + wave) * CHUNK;
  if (n0 >= Np) return;
  const u32 T = gT[b];
  float* S = stg[wave];
  u64* Q = qbuf[wave];
  STAGE_LOGITS(S, logits + ((size_t)b * Np + n0) * Cc)
  SOFTMAX_PROLOG(S)
  const int n_ = n0 + p;
  u32 qcnt = 0;
  #pragma unroll
  for (int k = 0; k < 21; ++k) {
    const int c = qd * 21 + k;
    bool sel = false;
    u64 key = 0;
    if (c > 0 && ev[k] > thr) {
      const u32 sb = __float_as_uint(__fdiv_rn(ev[k], s));
      u32 bk = (sb - BUCK_BASE) >> BUCK_SHIFT;
      if (bk > (u32)(NBUCK - 1)) bk = NBUCK - 1;
      if (bk >= T) {
        const u32 idx = (u32)(n_ * CM1 + (c - 1));
        key = ((u64)sb << 32) | (u32)(~idx);
        sel = true;
      }
    }
    const u64 bal = __ballot(sel);
    if (sel) Q[qcnt + (u32)__popcll(bal & ((1ull << lane) - 1ull))] = key;
    qcnt += (u32)__popcll(bal);
  }
  // drain (rare: ~0.7 survivors per wave on average)
  for (u32 qb = 0; qb < qcnt; qb += 64) {
    const u32 nn = qcnt - qb;
    if (lane < (int)nn) {
      const u64 key = Q[qb + lane];
      const u32 sb = (u32)(key >> 32);
      const u32 idx = ~(u32)key;
      const int pn = (int)(idx / CM1);
      const int c = (int)(idx - (u32)pn * CM1) + 1;
      float x1, y1, x2, y2;
      decode_box(b * Np + pn, c, reg, props, x1, y1, x2, y2);
      if (__fsub_rn(x2, x1) >= MIN_SZ && __fsub_rn(y2, y1) >= MIN_SZ) {
        u32 bk = (sb - BUCK_BASE) >> BUCK_SHIFT;
        if (bk > (u32)(NBUCK - 1)) bk = NBUCK - 1;
        const u32 pos = boffs[b * NBUCK + bk] + atomicAdd(&bfill[b * NBUCK + bk], 1u);
        if (pos < (u32)SELCAP) skeys[(size_t)b * SELCAP + pos] = key;
      }
    }
  }
}

// Intra-bucket rank sort, wave-per-bucket, src->dst (no in-place hazard).
// Bucket placement (suffix offsets) already gives global bucket-descending
// order; this completes the exact (score desc, idx asc) total order. Keys
// are unique, so rank = #{greater} is a bijection. Runs are tiny (avg ~10).
__global__ __launch_bounds__(256) void runsort_kernel(
    const u64* __restrict__ skeys, u64* __restrict__ skeys2,
    const u32* __restrict__ gT, const u32* __restrict__ boffs,
    const u32* __restrict__ bfill)
{
  const int b = blockIdx.y;
  const int wave = threadIdx.x >> 6, lane = threadIdx.x & 63;
  const u32 bk = blockIdx.x * RS_WPB + wave;
  if (bk >= (u32)NBUCK || bk < gT[b]) return;
  const u32 start = boffs[b * NBUCK + bk];
  u32 L = bfill[b * NBUCK + bk];
  if (L == 0 || start >= (u32)KSEL) return;     // empty or beyond top-2048
  if (start + L > (u32)SELCAP) L = SELCAP - start;
  const u64* run = skeys + (size_t)b * SELCAP + start;
  u64* dst = skeys2 + (size_t)b * SELCAP + start;
  if (L <= 128u) {
    // 2-chunk register rank sort: 64 unrolled broadcasts.
    const u64 k0 = (lane < (int)L) ? run[lane] : 0ull;
    const u64 k1 = (64 + lane < (int)L) ? run[64 + lane] : 0ull;
    u32 r0 = 0, r1 = 0;
    #pragma unroll
    for (int l = 0; l < 64; ++l) {
      const u64 o0 = shfl64(k0, l);
      const u64 o1 = shfl64(k1, l);
      r0 += (o0 > k0) + (o1 > k0);
      r1 += (o0 > k1) + (o1 > k1);
    }
    if (lane < (int)L) dst[r0] = k0;
    if (64 + lane < (int)L) dst[r1] = k1;
  } else {
    // Slow path (never expected): L2-hot global rank loop.
    for (u32 i = lane; i < L; i += 64) {
      const u64 k = run[i];
      u32 r = 0;
      for (u32 q = 0; q < L; ++q) r += (run[q] > k);
      dst[r] = k;
    }
  }
}

// Fused tail (no sort): load the globally-sorted top-2048, decode offset
// boxes/areas/scores to LDS, greedy NMS with on-the-fly IoU vs kept list
// (early-exit at 100), decode + write outputs. One block per image.
__global__ __launch_bounds__(1024) void tail_kernel(
    const u64* __restrict__ skeys2,
    const float* __restrict__ reg, const float* __restrict__ props,
    float* __restrict__ out)
{
  __shared__ float obx1[KSEL], oby1[KSEL], obx2[KSEL], oby2[KSEL];
  __shared__ float oar[KSEL], osc[KSEL];                         // 48 KB
  __shared__ unsigned short keptIdx[NDET];
  __shared__ u32 supflags[64];
  __shared__ u32 sh_kc;
  const int b = blockIdx.x;
  const int tid = threadIdx.x;
  const int wave = tid >> 6, lane = tid & 63;
  if (tid == 0) sh_kc = 0;

  // Decode top-2048 into LDS (class-offset box + area + score).
  for (int t = tid; t < KSEL; t += 1024) {
    const u64 key = skeys2[(size_t)b * SELCAP + t];
    float x1 = 0, y1 = 0, x2 = 0, y2 = 0, score = 0, lab = 0;
    if (key) {
      const u32 sb = (u32)(key >> 32);
      const u32 idx = ~(u32)key;
      const int n_ = (int)(idx / CM1);
      const int c = (int)(idx % CM1) + 1;
      score = __uint_as_float(sb);
      decode_box(b * Np + n_, c, reg, props, x1, y1, x2, y2);
      lab = (float)c;
    }
    const float offv = __fmul_rn(lab, LBLOFF);
    const float ox1 = __fadd_rn(x1, offv), oy1 = __fadd_rn(y1, offv);
    const float ox2 = __fadd_rn(x2, offv), oy2 = __fadd_rn(y2, offv);
    obx1[t] = ox1; oby1[t] = oy1; obx2[t] = ox2; oby2[t] = oy2;
    oar[t] = __fmul_rn(__fsub_rn(ox2, ox1), __fsub_rn(oy2, oy1));
    osc[t] = score;
  }
  __syncthreads();

  // Greedy NMS (zero-score holes are skipped by the todo mask).
  int kc = 0;
  for (int c = 0; c < 32 && kc < NDET; ++c) {
    if (tid < 64) supflags[tid] = 0;
    __syncthreads();
    // Phase 1 (all 16 waves): candidate j vs kept[k], k strided by wave.
    const int j = (c << 6) + lane;
    const float cx1 = obx1[j], cy1 = oby1[j], cx2 = obx2[j], cy2 = oby2[j], ca = oar[j];
    bool sup = false;
    for (int k = wave; k < kc; k += 16) {
      const int ki = keptIdx[k];
      const float ltx = fmaxf(cx1, obx1[ki]), lty = fmaxf(cy1, oby1[ki]);
      const float rbx = fminf(cx2, obx2[ki]), rby = fminf(cy2, oby2[ki]);
      const float wx = fmaxf(__fsub_rn(rbx, ltx), 0.f);
      const float wy = fmaxf(__fsub_rn(rby, lty), 0.f);
      const float inter = __fmul_rn(wx, wy);
      const float denom = __fadd_rn(__fsub_rn(__fadd_rn(ca, oar[ki]), inter), 1e-9f);
      if (__fdiv_rn(inter, denom) > NMS_TH) sup = true;
    }
    if (sup) supflags[lane] = 1u;   // benign same-value race
    __syncthreads();
    // Phase 2 (wave 0): sequential within-chunk resolve with per-lane IoU.
    if (wave == 0) {
      u64 rem = __ballot(supflags[lane] != 0u);
      u64 todo = __ballot(osc[j] > 0.f) & ~rem;
      int kcl = kc;
      while (todo && kcl < NDET) {
        const int jb = (int)__builtin_ctzll(todo);
        const int cj = (c << 6) + jb;
        if (lane == 0) keptIdx[kcl] = (unsigned short)cj;
        ++kcl;
        const float kx1 = obx1[cj], ky1 = oby1[cj], kx2 = obx2[cj], ky2 = oby2[cj], ka = oar[cj];
        const float ltx = fmaxf(kx1, cx1), lty = fmaxf(ky1, cy1);
        const float rbx = fminf(kx2, cx2), rby = fminf(ky2, cy2);
        const float wx = fmaxf(__fsub_rn(rbx, ltx), 0.f);
        const float wy = fmaxf(__fsub_rn(rby, lty), 0.f);
        const float inter = __fmul_rn(wx, wy);
        const float denom = __fadd_rn(__fsub_rn(__fadd_rn(ka, ca), inter), 1e-9f);
        const u64 w = __ballot(__fdiv_rn(inter, denom) > NMS_TH);
        rem |= w;
        todo &= ~rem;
        todo &= ~(1ull << jb);
      }
      if (lane == 0) sh_kc = (u32)kcl;
    }
    __syncthreads();
    kc = (int)sh_kc;
  }

  // Output: first min(kc,100) kept, padded with zeros / label -1.
  __syncthreads();
  const int kcl = (kc < NDET) ? kc : NDET;
  if (tid < NDET) {
    float bx1 = 0, by1 = 0, bx2 = 0, by2 = 0, sc = 0, lb = -1.f;
    if (tid < kcl) {
      const int i = keptIdx[tid];
      const u64 key = skeys2[(size_t)b * SELCAP + i];
      const u32 idx = ~(u32)key;
      const int n_ = (int)(idx / CM1);
      const int cc = (int)(idx % CM1) + 1;
      decode_box(b * Np + n_, cc, reg, props, bx1, by1, bx2, by2);
      sc = osc[i];
      lb = (float)cc;
    }
    float* ob = out + (size_t)b * NDET * 4;
    ob[tid * 4 + 0] = bx1; ob[tid * 4 + 1] = by1;
    ob[tid * 4 + 2] = bx2; ob[tid * 4 + 3] = by2;
    out[Bn * NDET * 4 + b * NDET + tid] = sc;
    out[Bn * NDET * 4 + Bn * NDET + b * NDET + tid] = lb;
  }
}

extern "C" void kernel_launch(void* const* d_in, const int* in_sizes, int n_in,
                              void* d_out, int out_size, void* d_ws, size_t ws_size,
                              hipStream_t stream) {
  const float* logits = (const float*)d_in[0];
  const float* reg    = (const float*)d_in[1];
  const float* props  = (const float*)d_in[2];
  float* out = (float*)d_out;
  char* ws = (char*)d_ws;

  // Layout: [header | ghist | bfill | skeys | skeys2]  <- memset 0 each call
  //         [boffs]                                    <- overwritten each call
  u32* gT = (u32*)ws;                          // 2 u32
  size_t off = 64;
  u32* ghist  = (u32*)(ws + off); off += (size_t)Bn * NBUCK * 4;   // 16 KB
  u32* bfill  = (u32*)(ws + off); off += (size_t)Bn * NBUCK * 4;   // 16 KB
  u64* skeys  = (u64*)(ws + off); off += (size_t)Bn * SELCAP * 8;  // 64 KB
  u64* skeys2 = (u64*)(ws + off); off += (size_t)Bn * SELCAP * 8;  // 64 KB
  const size_t memset_bytes = off;
  u32* boffs  = (u32*)(ws + off); off += (size_t)Bn * NBUCK * 4;   // 16 KB
  (void)ws_size;

  hipMemsetAsync(d_ws, 0, memset_bytes, stream);
  const int blocks_x = (Np + 4 * CHUNK - 1) / (4 * CHUNK);   // 782
  passA_kernel<<<dim3(blocks_x, Bn), 256, 0, stream>>>(logits, ghist);
  thresh_kernel<<<dim3(Bn), 64, 0, stream>>>(ghist, gT, boffs);
  passB_kernel<<<dim3(blocks_x, Bn), 256, 0, stream>>>(logits, reg, props, gT, boffs, bfill, skeys);
  runsort_kernel<<<dim3(NBUCK / RS_WPB, Bn), 256, 0, stream>>>(skeys, skeys2, gT, boffs, bfill);
  tail_kernel<<<dim3(Bn), 1024, 0, stream>>>(skeys2, reg, props, out);
}